// Round 1
// baseline (4058.678 us; speedup 1.0000x reference)
//
#include <hip/hip_runtime.h>
#include <cmath>

#define TPB 256

// ---- problem constants (fixed by setup_inputs) ----
constexpr int Bb = 32, Cc = 256, Ff = 1024, Oo = 201;
constexpr int H0 = 10, S0 = 8,  N0 = Bb * S0 * S0;   // 2048
constexpr int H1 = 20, S1 = 18, N1 = Bb * S1 * S1;   // 10368
constexpr int NT_ALL = N0 + N1;                      // 12416
constexpr int KC = Cc * 9;                           // 2304
constexpr int L5 = S0 * S0;                          // 64
constexpr int L4 = S1 * S1;                          // 324
constexpr int LT = L5 + L4;                          // 388

// ---- workspace layout (floats) ----
constexpr size_t OFF_H0   = 0;
constexpr size_t OFF_H1   = OFF_H0 + (size_t)Bb * Cc * H0 * H0;      // +819200
constexpr size_t OFF_C2   = OFF_H1 + (size_t)Bb * Cc * H1 * H1;      // +3276800
constexpr size_t OFF_GXY  = OFF_C2 + (size_t)NT_ALL * 6;
constexpr size_t OFF_FEAT = OFF_GXY + (size_t)NT_ALL * 18;
constexpr size_t OFF_SC   = OFF_FEAT + (size_t)NT_ALL * Ff;
constexpr size_t OFF_MX   = OFF_SC + (size_t)Bb * Oo * LT;
constexpr size_t OFF_SM   = OFF_MX + Bb;
constexpr size_t OFF_REG  = OFF_SM + Bb;
constexpr size_t WS_FLOATS = OFF_REG + Bb;                           // ~19.6M floats ~78.4MB

// ---- output layout (floats) ----
constexpr size_t O_LIK = 0;                 // 32*201
constexpr size_t O_BOX = O_LIK + Bb * Oo;   // 32*5
constexpr size_t O_NT  = O_BOX + Bb * 5;
constexpr size_t O_TD  = O_NT + Bb * 5;     // 12416*6
constexpr size_t O_REG = O_TD + (size_t)NT_ALL * 6;  // 81248

__device__ __forceinline__ float clampf(float x, float lo, float hi) {
    return fminf(fmaxf(x, lo), hi);
}

// =====================================================================
// Generic tiled GEMM: out(MxN) = gatherA(MxK) * Bw(NxK)^T  (+bias, act)
// MODE 0: A = im2col pad=1 from Asrc (NCHW, spatial HxH), rows m=(b,y,x)
//         epilogue: h[b][n][y][x] = relu(acc + bias[n])
// MODE 1: A = im2col pad=0 from Asrc (NCHW, spatial (S+2)x(S+2)),
//         rows m=(b,xx,yy); epilogue: out[m*6+n] = acc  (n<6)
// MODE 2: A = bilinear sample of Asrc (NCHW HxH) at gxy[m][j] coords,
//         k=(c*9+j); epilogue: out[m*1024+n] = relu(acc + bias[n])
// MODE 3: A = Asrc row-major MxK; epilogue scatter:
//         scores[(b*201+n)*LT + (yy*S+xx+POS)] = acc + bias[n]
// =====================================================================
template<int MODE, int H, int S, int M, int N, int KD, int POS>
__global__ __launch_bounds__(TPB)
void gemm_k(const float* __restrict__ Asrc, const float* __restrict__ gxy,
            const float* __restrict__ Bw, const float* __restrict__ bias,
            float* __restrict__ outp)
{
    constexpr int BM = 64, BN = 64, BK = 16;
    __shared__ float As[BK][BM + 4];
    __shared__ float Bs[BK][BN + 4];
    const int tid = threadIdx.x;
    const int tx = tid & 15, ty = tid >> 4;
    const int bm = blockIdx.x * BM, bn = blockIdx.y * BN;
    float acc[4][4] = {};

    for (int kb = 0; kb < KD; kb += BK) {
        // ---- load A tile (64x16) ----
        #pragma unroll
        for (int l = 0; l < 4; l++) {
            int idx = l * 256 + tid;
            int ml = idx >> 4, kl = idx & 15;
            int mG = bm + ml, kG = kb + kl;
            float v = 0.f;
            if (mG < M) {
                if constexpr (MODE == 0) {
                    int b = mG / (H * H); int rem = mG - b * (H * H);
                    int y = rem / H, x = rem - (rem / H) * H;
                    int ci = kG / 9; int t = kG - ci * 9;
                    int ky = t / 3, kx = t - (t / 3) * 3;
                    int yy = y + ky - 1, xx = x + kx - 1;
                    if (yy >= 0 && yy < H && xx >= 0 && xx < H)
                        v = Asrc[(((size_t)b * Cc + ci) * H + yy) * H + xx];
                } else if constexpr (MODE == 1) {
                    constexpr int SS = S * S, HH = S + 2;
                    int b = mG / SS; int rem = mG - b * SS;
                    int xq = rem / S, yq = rem - (rem / S) * S;
                    int ci = kG / 9; int t = kG - ci * 9;
                    int ky = t / 3, kx = t - (t / 3) * 3;
                    v = Asrc[(((size_t)b * Cc + ci) * HH + yq + ky) * HH + xq + kx];
                } else if constexpr (MODE == 2) {
                    constexpr int SS = S * S;
                    int b = mG / SS;
                    int c = kG / 9; int j = kG - c * 9;
                    float gx = gxy[(size_t)mG * 18 + j];
                    float gy = gxy[(size_t)mG * 18 + 9 + j];
                    float xf = floorf(gx), yf = floorf(gy);
                    float wx = gx - xf, wy = gy - yf;
                    int ix = (int)xf, iy = (int)yf;
                    const float* xb = Asrc + ((size_t)b * Cc + c) * (H * H);
                    int cx0 = min(max(ix, 0), H - 1), cx1 = min(max(ix + 1, 0), H - 1);
                    int cy0 = min(max(iy, 0), H - 1), cy1 = min(max(iy + 1, 0), H - 1);
                    float vx0 = (ix >= 0 && ix < H) ? 1.f : 0.f;
                    float vx1 = (ix + 1 >= 0 && ix + 1 < H) ? 1.f : 0.f;
                    float vy0 = (iy >= 0 && iy < H) ? 1.f : 0.f;
                    float vy1 = (iy + 1 >= 0 && iy + 1 < H) ? 1.f : 0.f;
                    float v00 = xb[cy0 * H + cx0] * vy0 * vx0;
                    float v01 = xb[cy0 * H + cx1] * vy0 * vx1;
                    float v10 = xb[cy1 * H + cx0] * vy1 * vx0;
                    float v11 = xb[cy1 * H + cx1] * vy1 * vx1;
                    v = v00 * (1.f - wy) * (1.f - wx) + v01 * (1.f - wy) * wx
                      + v10 * wy * (1.f - wx) + v11 * wy * wx;
                } else {
                    v = Asrc[(size_t)mG * KD + kG];
                }
            }
            As[kl][ml] = v;
        }
        // ---- load B tile (16x64): Bw is [N][KD] row-major ----
        #pragma unroll
        for (int l = 0; l < 4; l++) {
            int idx = l * 256 + tid;
            int nl = idx >> 4, kl = idx & 15;
            int nG = bn + nl, kG = kb + kl;
            Bs[kl][nl] = (nG < N) ? Bw[(size_t)nG * KD + kG] : 0.f;
        }
        __syncthreads();
        #pragma unroll
        for (int kk = 0; kk < BK; kk++) {
            float4 a = *(const float4*)&As[kk][ty * 4];
            float4 b = *(const float4*)&Bs[kk][tx * 4];
            float av[4] = {a.x, a.y, a.z, a.w};
            float bv[4] = {b.x, b.y, b.z, b.w};
            #pragma unroll
            for (int i = 0; i < 4; i++)
                #pragma unroll
                for (int j = 0; j < 4; j++)
                    acc[i][j] = fmaf(av[i], bv[j], acc[i][j]);
        }
        __syncthreads();
    }

    // ---- epilogue ----
    #pragma unroll
    for (int i = 0; i < 4; i++) {
        int mG = bm + ty * 4 + i;
        if (mG >= M) continue;
        #pragma unroll
        for (int j = 0; j < 4; j++) {
            int nG = bn + tx * 4 + j;
            float r = acc[i][j];
            if constexpr (MODE == 0) {
                int b = mG / (H * H); int rem = mG - b * (H * H);
                int y = rem / H, x = rem - (rem / H) * H;
                outp[(((size_t)b * Cc + nG) * H + y) * H + x] = fmaxf(r + bias[nG], 0.f);
            } else if constexpr (MODE == 1) {
                if (nG < N) outp[(size_t)mG * 6 + nG] = r;
            } else if constexpr (MODE == 2) {
                outp[(size_t)mG * Ff + nG] = fmaxf(r + bias[nG], 0.f);
            } else {
                if (nG < N) {
                    constexpr int SS = S * S;
                    int b = mG / SS; int rem = mG - b * SS;
                    int xq = rem / S, yq = rem - (rem / S) * S;
                    int pos = yq * S + xq + POS;
                    outp[((size_t)b * Oo + nG) * LT + pos] = r + bias[nG];
                }
            }
        }
    }
}

// ====================================================================
// theta / theta_diff / sampling-coordinate kernel (one thread per n)
// n ordering: scale0 rows 0..2047 as (b, xx, yy); then scale1.
// ====================================================================
__global__ __launch_bounds__(TPB)
void theta_aux_k(const float* __restrict__ c2, const int* __restrict__ checkp,
                 float* __restrict__ td, float* __restrict__ gxy)
{
    int n = blockIdx.x * TPB + threadIdx.x;
    if (n >= NT_ALL) return;
    float omc = 1.0f - (float)checkp[0];
    const float I[6] = {1.f, 0.f, 0.f, 0.f, 1.f, 0.f};
    float th[6];
    #pragma unroll
    for (int i = 0; i < 6; i++) {
        float v = c2[(size_t)n * 6 + i] * omc + I[i];
        th[i] = v;
        td[(size_t)n * 6 + i] = I[i] - v;
    }
    int S, loc;
    if (n < N0) { S = S0; loc = n; } else { S = S1; loc = n - N0; }
    int SS = S * S;
    int rem = loc % SS;
    int xx = rem / S, yy = rem % S;
    #pragma unroll
    for (int ky = 0; ky < 3; ky++)
        #pragma unroll
        for (int kx = 0; kx < 3; kx++) {
            float bx = (float)(kx - 1), by = (float)(ky - 1);
            gxy[(size_t)n * 18 + ky * 3 + kx]     = th[0] * bx + th[1] * by + th[2] + 1.0f + (float)xx;
            gxy[(size_t)n * 18 + 9 + ky * 3 + kx] = th[3] * bx + th[4] * by + th[5] + 1.0f + (float)yy;
        }
}

// per-batch max + sum(exp) over all 201*388 scores
__global__ __launch_bounds__(TPB)
void softstats_k(const float* __restrict__ sc, float* __restrict__ mx, float* __restrict__ sm)
{
    int b = blockIdx.x, tid = threadIdx.x;
    const float* p = sc + (size_t)b * Oo * LT;
    constexpr int PER = Oo * LT;
    __shared__ float red[TPB];
    float m = -3.4e38f;
    for (int i = tid; i < PER; i += TPB) m = fmaxf(m, p[i]);
    red[tid] = m;
    for (int off = 128; off; off >>= 1) { __syncthreads(); if (tid < off) red[tid] = fmaxf(red[tid], red[tid + off]); }
    __syncthreads();
    m = red[0];
    __syncthreads();
    float s = 0.f;
    for (int i = tid; i < PER; i += TPB) s += expf(p[i] - m);
    red[tid] = s;
    for (int off = 128; off; off >>= 1) { __syncthreads(); if (tid < off) red[tid] += red[tid + off]; }
    __syncthreads();
    if (tid == 0) { mx[b] = m; sm[b] = red[0]; }
}

// likelihood[b][o] = sum_pos exp(score - mx) / sm
__global__ __launch_bounds__(TPB)
void lik_k(const float* __restrict__ sc, const float* __restrict__ mx,
           const float* __restrict__ sm, float* __restrict__ lik)
{
    int b = blockIdx.x, o = threadIdx.x;
    if (o >= Oo) return;
    const float* p = sc + ((size_t)b * Oo + o) * LT;
    float m = mx[b];
    float s = 0.f;
    for (int i = 0; i < LT; i++) s += expf(p[i] - m);
    lik[b * Oo + o] = s / sm[b];
}

// pred argmax, per-scale argmax/conf, boxes + NT boxes + reg partial
__global__ __launch_bounds__(TPB)
void box_k(const float* __restrict__ sc, const float* __restrict__ lik,
           const float* __restrict__ mx, const float* __restrict__ sm,
           const float* __restrict__ gxy, const int* __restrict__ imdp,
           float* __restrict__ boxes, float* __restrict__ boxesNT,
           float* __restrict__ regpart)
{
    int b = blockIdx.x, tid = threadIdx.x;
    __shared__ float sv[TPB];
    __shared__ int si[TPB];

    // pred = argmax_o likelihood (first max)
    float v = (tid < Oo) ? lik[b * Oo + tid] : -3.4e38f;
    sv[tid] = v; si[tid] = tid;
    for (int off = 128; off; off >>= 1) {
        __syncthreads();
        if (tid < off) {
            float v2 = sv[tid + off]; int i2 = si[tid + off];
            if (v2 > sv[tid] || (v2 == sv[tid] && i2 < si[tid])) { sv[tid] = v2; si[tid] = i2; }
        }
    }
    __syncthreads();
    int pred = si[0];
    __syncthreads();

    const float* p = sc + ((size_t)b * Oo + pred) * LT;
    float b5 = -3.4e38f; int i5 = 1 << 30;
    float b4 = -3.4e38f; int i4 = 1 << 30;
    for (int pos = tid; pos < LT; pos += TPB) {
        float s = p[pos];
        if (pos < L5) { if (s > b5) { b5 = s; i5 = pos; } }
        else { int q = pos - L5; if (s > b4) { b4 = s; i4 = q; } }
    }
    sv[tid] = b5; si[tid] = i5;
    for (int off = 128; off; off >>= 1) {
        __syncthreads();
        if (tid < off) {
            float v2 = sv[tid + off]; int i2 = si[tid + off];
            if (v2 > sv[tid] || (v2 == sv[tid] && i2 < si[tid])) { sv[tid] = v2; si[tid] = i2; }
        }
    }
    __syncthreads();
    float m5 = sv[0]; int d5 = si[0];
    __syncthreads();
    sv[tid] = b4; si[tid] = i4;
    for (int off = 128; off; off >>= 1) {
        __syncthreads();
        if (tid < off) {
            float v2 = sv[tid + off]; int i2 = si[tid + off];
            if (v2 > sv[tid] || (v2 == sv[tid] && i2 < si[tid])) { sv[tid] = v2; si[tid] = i2; }
        }
    }
    __syncthreads();
    float m4 = sv[0]; int d4 = si[0];

    if (tid == 0) {
        float m = mx[b], s = sm[b];
        float conf5 = expf(m5 - m) / s;
        float conf4 = expf(m4 - m) / s;
        float imd = (float)imdp[0];
        float lo = 0.f, hi = imd - 1.f;

        // scale 0 (S=8, H-1=9)
        int xx5 = d5 % S0, yy5 = d5 / S0;
        int n5 = b * (S0 * S0) + xx5 * S0 + yy5;
        const float* g = gxy + (size_t)n5 * 18;
        float txm = 1e30f, txM = -1e30f, tym = 1e30f, tyM = -1e30f;
        for (int j = 0; j < 9; j++) {
            float tx = g[j] / 9.f, ty = g[9 + j] / 9.f;
            txm = fminf(txm, tx); txM = fmaxf(txM, tx);
            tym = fminf(tym, ty); tyM = fmaxf(tyM, ty);
        }
        float box5[5] = { clampf(txm * imd, lo, hi), clampf(tym * imd, lo, hi),
                          clampf(txM * imd, lo, hi), clampf(tyM * imd, lo, hi), conf5 };
        float nt5[5]  = { clampf((float)xx5 / 9.f * imd, lo, hi), clampf((float)yy5 / 9.f * imd, lo, hi),
                          clampf((float)(xx5 + 2) / 9.f * imd, lo, hi), clampf((float)(yy5 + 2) / 9.f * imd, lo, hi), conf5 };

        // scale 1 (S=18, H-1=19)
        int xx4 = d4 % S1, yy4 = d4 / S1;
        int n4 = N0 + b * (S1 * S1) + xx4 * S1 + yy4;
        const float* g4 = gxy + (size_t)n4 * 18;
        float txm4 = 1e30f, txM4 = -1e30f, tym4 = 1e30f, tyM4 = -1e30f;
        for (int j = 0; j < 9; j++) {
            float tx = g4[j] / 19.f, ty = g4[9 + j] / 19.f;
            txm4 = fminf(txm4, tx); txM4 = fmaxf(txM4, tx);
            tym4 = fminf(tym4, ty); tyM4 = fmaxf(tyM4, ty);
        }
        float box4[5] = { clampf(txm4 * imd, lo, hi), clampf(tym4 * imd, lo, hi),
                          clampf(txM4 * imd, lo, hi), clampf(tyM4 * imd, lo, hi), conf4 };
        float nt4[5]  = { clampf((float)xx4 / 19.f * imd, lo, hi), clampf((float)yy4 / 19.f * imd, lo, hi),
                          clampf((float)(xx4 + 2) / 19.f * imd, lo, hi), clampf((float)(yy4 + 2) / 19.f * imd, lo, hi), conf4 };

        int mi = (conf4 > conf5) ? 1 : 0;
        for (int i = 0; i < 5; i++) {
            boxes[b * 5 + i]   = mi ? box4[i] : box5[i];
            boxesNT[b * 5 + i] = mi ? nt4[i] : nt5[i];
        }
        regpart[b] = fmaxf(conf4 - conf5, 0.f);
    }
}

__global__ void reg_k(const float* __restrict__ regpart, float* __restrict__ outreg)
{
    if (threadIdx.x == 0) {
        float s = 0.f;
        for (int b = 0; b < Bb; b++) s += regpart[b];
        outreg[0] = s;
    }
}

__global__ void sentinel_k(float* out, int n)
{
    int i = blockIdx.x * 256 + threadIdx.x;
    if (i < n) out[i] = 12345.0f;
}

extern "C" void kernel_launch(void* const* d_in, const int* in_sizes, int n_in,
                              void* d_out, int out_size, void* d_ws, size_t ws_size,
                              hipStream_t stream)
{
    const float* x0 = (const float*)d_in[0];
    const float* x1 = (const float*)d_in[1];
    const float* w0 = (const float*)d_in[2];
    const float* b0 = (const float*)d_in[3];
    const float* w1 = (const float*)d_in[4];
    const float* cw = (const float*)d_in[5];
    const float* cb = (const float*)d_in[6];
    const float* lw = (const float*)d_in[7];
    const float* lb = (const float*)d_in[8];
    const int* checkp = (const int*)d_in[9];
    const int* imdp   = (const int*)d_in[10];

    if (ws_size < WS_FLOATS * sizeof(float)) {
        // unambiguous sentinel so a too-small workspace is distinguishable
        sentinel_k<<<dim3((out_size + 255) / 256), dim3(256), 0, stream>>>((float*)d_out, out_size);
        return;
    }

    float* ws   = (float*)d_ws;
    float* h0   = ws + OFF_H0;
    float* h1   = ws + OFF_H1;
    float* c2   = ws + OFF_C2;
    float* gxy  = ws + OFF_GXY;
    float* feat = ws + OFF_FEAT;
    float* sc   = ws + OFF_SC;
    float* mx   = ws + OFF_MX;
    float* sm   = ws + OFF_SM;
    float* rp   = ws + OFF_REG;

    float* out   = (float*)d_out;
    float* o_lik = out + O_LIK;
    float* o_box = out + O_BOX;
    float* o_nt  = out + O_NT;
    float* o_td  = out + O_TD;
    float* o_reg = out + O_REG;

    dim3 blk(TPB);

    // conv1 (+bias, relu) -> h, both scales
    gemm_k<0, H0, 1, Bb * H0 * H0, Cc, KC, 0><<<dim3(50, 4), blk, 0, stream>>>(x0, nullptr, w0, b0, h0);
    gemm_k<0, H1, 1, Bb * H1 * H1, Cc, KC, 0><<<dim3(200, 4), blk, 0, stream>>>(x1, nullptr, w0, b0, h1);

    // conv2 (6ch, no pad) -> c2out rows (b,xx,yy)
    gemm_k<1, H0, S0, N0, 6, KC, 0><<<dim3(32, 1), blk, 0, stream>>>(h0, nullptr, w1, nullptr, c2);
    gemm_k<1, H1, S1, N1, 6, KC, 0><<<dim3(162, 1), blk, 0, stream>>>(h1, nullptr, w1, nullptr, c2 + (size_t)N0 * 6);

    // theta, theta_diff output, sampling coords
    theta_aux_k<<<dim3((NT_ALL + TPB - 1) / TPB), blk, 0, stream>>>(c2, checkp, o_td, gxy);

    // fused bilinear-sample GEMM -> relu(feat)
    gemm_k<2, H0, S0, N0, Ff, KC, 0><<<dim3(32, 16), blk, 0, stream>>>(x0, gxy, cw, cb, feat);
    gemm_k<2, H1, S1, N1, Ff, KC, 0><<<dim3(162, 16), blk, 0, stream>>>(x1, gxy + (size_t)N0 * 18, cw, cb, feat + (size_t)N0 * Ff);

    // feat -> scores scatter
    gemm_k<3, 1, S0, N0, Oo, Ff, 0><<<dim3(32, 4), blk, 0, stream>>>(feat, nullptr, lw, lb, sc);
    gemm_k<3, 1, S1, N1, Oo, Ff, L5><<<dim3(162, 4), blk, 0, stream>>>(feat + (size_t)N0 * Ff, nullptr, lw, lb, sc);

    // softmax stats, likelihood, boxes, reg
    softstats_k<<<dim3(Bb), blk, 0, stream>>>(sc, mx, sm);
    lik_k<<<dim3(Bb), blk, 0, stream>>>(sc, mx, sm, o_lik);
    box_k<<<dim3(Bb), blk, 0, stream>>>(sc, o_lik, mx, sm, gxy, imdp, o_box, o_nt, rp);
    reg_k<<<dim3(1), dim3(64), 0, stream>>>(rp, o_reg);
}

// Round 2
// 1870.022 us; speedup vs baseline: 2.1704x; 2.1704x over previous
//
#include <hip/hip_runtime.h>
#include <cmath>

#define TPB 256

// ---- problem constants (fixed by setup_inputs) ----
constexpr int Bb = 32, Cc = 256, Ff = 1024, Oo = 201;
constexpr int H0 = 10, S0 = 8,  N0 = Bb * S0 * S0;   // 2048
constexpr int H1 = 20, S1 = 18, N1 = Bb * S1 * S1;   // 10368
constexpr int NT_ALL = N0 + N1;                      // 12416
constexpr int KC = Cc * 9;                           // 2304
constexpr int L5 = S0 * S0;                          // 64
constexpr int L4 = S1 * S1;                          // 324
constexpr int LT = L5 + L4;                          // 388

// ---- element counts ----
constexpr size_t SZ_CW = (size_t)Ff * KC;       // 2,359,296
constexpr size_t SZ_W0 = (size_t)Cc * KC;       // 589,824
constexpr size_t SZ_LW = (size_t)Oo * Ff;       // 205,824
constexpr size_t NFEAT = (size_t)NT_ALL * Ff;   // 12,713,984

// ---- workspace byte offsets (time-disjoint aliasing) ----
constexpr size_t B_CWH = 0;
constexpr size_t B_CWL = B_CWH + SZ_CW * 2;            // 4,718,592
constexpr size_t B_W0H = B_CWL + SZ_CW * 2;            // 9,437,184
constexpr size_t B_W0L = B_W0H + SZ_W0 * 2;            // 10,616,832
constexpr size_t B_GXY = B_W0L + SZ_W0 * 2;            // 11,796,480
constexpr size_t B_LWH = B_GXY + (size_t)NT_ALL * 18 * 4; // 12,690,432
constexpr size_t B_LWL = B_LWH + SZ_LW * 2;            // 13,102,080
constexpr size_t B_FEATH = B_LWL + SZ_LW * 2;          // 13,513,728
constexpr size_t B_FEATL = B_FEATH + NFEAT * 2;        // 38,941,696
constexpr size_t B_MX  = B_FEATL + NFEAT * 2;          // 64,369,664
constexpr size_t B_SM  = B_MX + 128;
constexpr size_t B_RP  = B_SM + 128;
constexpr size_t B_END = B_RP + 128;                   // ~64.4 MB
// aliases (disjoint lifetimes):
constexpr size_t B_SC  = B_CWH;    // sc: 2,495,616*4 = 9,982,464 B, spans cw+w0 regions (dead by then)
constexpr size_t B_C2  = B_W0H;    // c2: 297,984 B over dead w0 splits
constexpr size_t B_H0  = B_FEATH;  // h0: 3,276,800 B over not-yet-written feat
constexpr size_t B_H1  = B_H0 + (size_t)Bb * Cc * H0 * H0 * 4;  // h1: 13,107,200 B

// ---- output layout (floats) ----
constexpr size_t O_LIK = 0;
constexpr size_t O_BOX = O_LIK + Bb * Oo;
constexpr size_t O_NT  = O_BOX + Bb * 5;
constexpr size_t O_TD  = O_NT + Bb * 5;
constexpr size_t O_REG = O_TD + (size_t)NT_ALL * 6;

typedef __attribute__((ext_vector_type(8))) short bf16x8;
typedef __attribute__((ext_vector_type(4))) float f32x4;

__device__ __forceinline__ short f2bf(float f) {
    unsigned u = __builtin_bit_cast(unsigned, f);
    u += 0x7fffu + ((u >> 16) & 1u);
    return (short)(u >> 16);
}
__device__ __forceinline__ float bf2f(short s) {
    unsigned u = ((unsigned)(unsigned short)s) << 16;
    return __builtin_bit_cast(float, u);
}
__device__ __forceinline__ float clampf(float x, float lo, float hi) {
    return fminf(fmaxf(x, lo), hi);
}

// =====================================================================
// split kernels: fp32 -> (hi, lo) bf16.  splitp also permutes K:
// src k = c*9 + t  ->  dst k' = t*256 + c   (per row of length 2304)
// =====================================================================
__global__ __launch_bounds__(TPB)
void splitp_k(const float* __restrict__ src, short* __restrict__ hi,
              short* __restrict__ lo, int nrows)
{
    int idx = blockIdx.x * TPB + threadIdx.x;
    int total = nrows * KC;
    if (idx >= total) return;
    int row = idx / KC, k = idx - row * KC;
    int c = k / 9, t = k - c * 9;
    float v = src[idx];
    short hs = f2bf(v);
    size_t dst = (size_t)row * KC + t * 256 + c;
    hi[dst] = hs;
    lo[dst] = f2bf(v - bf2f(hs));
}

__global__ __launch_bounds__(TPB)
void split_k(const float* __restrict__ src, short* __restrict__ hi,
             short* __restrict__ lo, int n)
{
    int idx = blockIdx.x * TPB + threadIdx.x;
    if (idx >= n) return;
    float v = src[idx];
    short hs = f2bf(v);
    hi[idx] = hs;
    lo[idx] = f2bf(v - bf2f(hs));
}

// =====================================================================
// Split-bf16 MFMA GEMM: out(MxN) = A(MxK) * Bw(NxK)^T (+bias, act)
// Block 128x128, BK=32, 4 waves (64x64 each), mfma_f32_16x16x32_bf16,
// 3 MFMAs per tile pair (hi*hi + lo*hi + hi*lo).
// MODE 0: A = im2col pad=1 of Asrc (NCHW HxH), K permuted (t*256+c);
//         epilogue h[b][n][y][x] = relu(acc+bias[n])  (fp32)
// MODE 2: A = bilinear sample of Asrc at gxy coords, K permuted (j*256+c);
//         epilogue feat hi/lo bf16 = split(relu(acc+bias[n]))
// MODE 3: A = pre-split feat rows (AsrcH/AsrcL), K unpermuted;
//         epilogue scatter sc[(b*201+n)*388 + pos] = acc+bias[n]
// =====================================================================
template<int MODE, int H, int S, int M, int N, int KD, int POS>
__global__ __launch_bounds__(TPB, 2)
void mgemm(const float* __restrict__ Asrc,
           const short* __restrict__ AsrcH, const short* __restrict__ AsrcL,
           const float* __restrict__ gxy,
           const short* __restrict__ Bh, const short* __restrict__ Bl,
           const float* __restrict__ bias,
           float* __restrict__ outF, short* __restrict__ outH, short* __restrict__ outL)
{
    __shared__ short As[2][4][128][8];   // [hi/lo][kgrp][m][e] : 16KB
    __shared__ short Bs[2][4][128][8];   // 16KB
    const int tid = threadIdx.x;
    const int lane = tid & 63;
    const int wid = tid >> 6;
    const int wm = (wid >> 1) * 64, wn = (wid & 1) * 64;
    const int ml = tid & 127, kg0 = tid >> 7;
    const int bm = blockIdx.x * 128, bn = blockIdx.y * 128;

    f32x4 acc[4][4];
    #pragma unroll
    for (int i = 0; i < 4; i++)
        #pragma unroll
        for (int j = 0; j < 4; j++)
            acc[i][j] = (f32x4){0.f, 0.f, 0.f, 0.f};

    const int mG = bm + ml;
    int bA = 0, yA = 0, xA = 0;
    if constexpr (MODE == 0) {
        bA = mG / (H * H); int rem = mG - bA * (H * H);
        yA = rem / H; xA = rem - yA * H;
    } else if constexpr (MODE == 2) {
        bA = mG / (S * S);
    }
    const int nG = bn + ml;

    for (int kb = 0; kb < KD; kb += 32) {
        // ---------- stage A ----------
        if constexpr (MODE == 0) {
            const int t = kb >> 8;
            const int ky = t / 3 - 1, kx = t - (t / 3) * 3 - 1;
            const int yy = yA + ky, xx = xA + kx;
            const bool ok = (yy >= 0 && yy < H && xx >= 0 && xx < H);
            const float* bp = Asrc + (size_t)bA * Cc * (H * H) + yy * H + xx;
            const int c0 = kb & 255;
            #pragma unroll
            for (int hh = 0; hh < 2; hh++) {
                int kg = kg0 + 2 * hh;
                bf16x8 hv, lv;
                #pragma unroll
                for (int e = 0; e < 8; e++) {
                    int c = c0 + kg * 8 + e;
                    float v = ok ? bp[(size_t)c * (H * H)] : 0.f;
                    short hs = f2bf(v); hv[e] = hs;
                    lv[e] = f2bf(v - bf2f(hs));
                }
                *(bf16x8*)&As[0][kg][ml][0] = hv;
                *(bf16x8*)&As[1][kg][ml][0] = lv;
            }
        } else if constexpr (MODE == 2) {
            const int j = kb >> 8, c0 = kb & 255;
            const float gx = gxy[(size_t)mG * 18 + j];
            const float gy = gxy[(size_t)mG * 18 + 9 + j];
            const float xf = floorf(gx), yf = floorf(gy);
            const float wx = gx - xf, wy = gy - yf;
            const int ix = (int)xf, iy = (int)yf;
            const int cx0 = min(max(ix, 0), H - 1), cx1 = min(max(ix + 1, 0), H - 1);
            const int cy0 = min(max(iy, 0), H - 1), cy1 = min(max(iy + 1, 0), H - 1);
            const float vx0 = (ix >= 0 && ix < H) ? 1.f : 0.f;
            const float vx1 = (ix + 1 >= 0 && ix + 1 < H) ? 1.f : 0.f;
            const float vy0 = (iy >= 0 && iy < H) ? 1.f : 0.f;
            const float vy1 = (iy + 1 >= 0 && iy + 1 < H) ? 1.f : 0.f;
            const float w00 = (1.f - wy) * (1.f - wx) * vy0 * vx0;
            const float w01 = (1.f - wy) * wx * vy0 * vx1;
            const float w10 = wy * (1.f - wx) * vy1 * vx0;
            const float w11 = wy * wx * vy1 * vx1;
            const int o00 = cy0 * H + cx0, o01 = cy0 * H + cx1;
            const int o10 = cy1 * H + cx0, o11 = cy1 * H + cx1;
            const float* bp = Asrc + (size_t)(bA * Cc + c0) * (H * H);
            #pragma unroll
            for (int hh = 0; hh < 2; hh++) {
                int kg = kg0 + 2 * hh;
                bf16x8 hv, lv;
                #pragma unroll
                for (int e = 0; e < 8; e++) {
                    const float* cp = bp + (size_t)(kg * 8 + e) * (H * H);
                    float v = cp[o00] * w00 + cp[o01] * w01 + cp[o10] * w10 + cp[o11] * w11;
                    short hs = f2bf(v); hv[e] = hs;
                    lv[e] = f2bf(v - bf2f(hs));
                }
                *(bf16x8*)&As[0][kg][ml][0] = hv;
                *(bf16x8*)&As[1][kg][ml][0] = lv;
            }
        } else { // MODE 3
            #pragma unroll
            for (int hh = 0; hh < 2; hh++) {
                int kg = kg0 + 2 * hh;
                *(bf16x8*)&As[0][kg][ml][0] = *(const bf16x8*)(AsrcH + (size_t)mG * KD + kb + kg * 8);
                *(bf16x8*)&As[1][kg][ml][0] = *(const bf16x8*)(AsrcL + (size_t)mG * KD + kb + kg * 8);
            }
        }
        // ---------- stage B ----------
        #pragma unroll
        for (int hh = 0; hh < 2; hh++) {
            int kg = kg0 + 2 * hh;
            bf16x8 hv = {}, lv = {};
            if (nG < N) {
                hv = *(const bf16x8*)(Bh + (size_t)nG * KD + kb + kg * 8);
                lv = *(const bf16x8*)(Bl + (size_t)nG * KD + kb + kg * 8);
            }
            *(bf16x8*)&Bs[0][kg][ml][0] = hv;
            *(bf16x8*)&Bs[1][kg][ml][0] = lv;
        }
        __syncthreads();
        // ---------- compute ----------
        {
            const int kq = lane >> 4, r = lane & 15;
            bf16x8 ah[4], al[4], bhf[4], blf[4];
            #pragma unroll
            for (int i = 0; i < 4; i++) {
                ah[i]  = *(const bf16x8*)&As[0][kq][wm + i * 16 + r][0];
                al[i]  = *(const bf16x8*)&As[1][kq][wm + i * 16 + r][0];
                bhf[i] = *(const bf16x8*)&Bs[0][kq][wn + i * 16 + r][0];
                blf[i] = *(const bf16x8*)&Bs[1][kq][wn + i * 16 + r][0];
            }
            #pragma unroll
            for (int i = 0; i < 4; i++)
                #pragma unroll
                for (int j = 0; j < 4; j++) {
                    acc[i][j] = __builtin_amdgcn_mfma_f32_16x16x32_bf16(ah[i], bhf[j], acc[i][j], 0, 0, 0);
                    acc[i][j] = __builtin_amdgcn_mfma_f32_16x16x32_bf16(al[i], bhf[j], acc[i][j], 0, 0, 0);
                    acc[i][j] = __builtin_amdgcn_mfma_f32_16x16x32_bf16(ah[i], blf[j], acc[i][j], 0, 0, 0);
                }
        }
        __syncthreads();
    }

    // ---------- epilogue ----------
    const int kq = lane >> 4, rr = lane & 15;
    #pragma unroll
    for (int i = 0; i < 4; i++) {
        #pragma unroll
        for (int r = 0; r < 4; r++) {
            const int gm = bm + wm + i * 16 + kq * 4 + r;
            #pragma unroll
            for (int j = 0; j < 4; j++) {
                const int gn = bn + wn + j * 16 + rr;
                float v = acc[i][j][r];
                if constexpr (MODE == 0) {
                    int bq = gm / (H * H); int rem = gm - bq * (H * H);
                    int yq = rem / H; int xq = rem - yq * H;
                    outF[(((size_t)bq * Cc + gn) * H + yq) * H + xq] = fmaxf(v + bias[gn], 0.f);
                } else if constexpr (MODE == 2) {
                    float q = fmaxf(v + bias[gn], 0.f);
                    short hs = f2bf(q);
                    outH[(size_t)gm * Ff + gn] = hs;
                    outL[(size_t)gm * Ff + gn] = f2bf(q - bf2f(hs));
                } else {
                    if (gn < N) {
                        int bq = gm / (S * S); int rem = gm - bq * (S * S);
                        int xq = rem / S; int yq = rem - xq * S;
                        outF[((size_t)bq * Oo + gn) * LT + (yq * S + xq + POS)] = v + bias[gn];
                    }
                }
            }
        }
    }
}

// =====================================================================
// conv2: N=6 tiny conv. 32 rows/block, 8 ci-groups, w1 in LDS.
// rows m=(b,xq,yq); A el = h[b][ci][yq+ky][xq+kx]
// =====================================================================
__global__ __launch_bounds__(TPB)
void conv2_k(const float* __restrict__ h0, const float* __restrict__ h1,
             const float* __restrict__ w1, float* __restrict__ c2)
{
    __shared__ float wl[6][KC];       // 55.3 KB
    __shared__ float part[8][32][6];  // 6 KB
    const int tid = threadIdx.x;
    for (int i = tid; i < 6 * KC; i += TPB) wl[i / KC][i - (i / KC) * KC] = w1[i];
    __syncthreads();
    const int row = blockIdx.x * 32 + (tid & 31);
    const int cig = tid >> 5;
    const float* hsrc; int H, S, loc;
    if (row < N0) { hsrc = h0; H = H0; S = S0; loc = row; }
    else          { hsrc = h1; H = H1; S = S1; loc = row - N0; }
    int SS = S * S;
    int b = loc / SS; int rem = loc - b * SS;
    int xq = rem / S; int yq = rem - xq * S;
    float acc[6] = {};
    for (int ci = cig * 32; ci < cig * 32 + 32; ci++) {
        const float* hp = hsrc + ((size_t)(b * Cc + ci) * H + yq) * H + xq;
        #pragma unroll
        for (int ky = 0; ky < 3; ky++)
            #pragma unroll
            for (int kx = 0; kx < 3; kx++) {
                float a = hp[ky * H + kx];
                int kk = ci * 9 + ky * 3 + kx;
                #pragma unroll
                for (int n = 0; n < 6; n++) acc[n] = fmaf(a, wl[n][kk], acc[n]);
            }
    }
    #pragma unroll
    for (int n = 0; n < 6; n++) part[cig][tid & 31][n] = acc[n];
    __syncthreads();
    if (cig == 0) {
        #pragma unroll
        for (int n = 0; n < 6; n++) {
            float s = 0.f;
            for (int g = 0; g < 8; g++) s += part[g][tid & 31][n];
            c2[(size_t)row * 6 + n] = s;
        }
    }
}

// ====================================================================
// theta / theta_diff / sampling-coordinate kernel  (verified round 1)
// ====================================================================
__global__ __launch_bounds__(TPB)
void theta_aux_k(const float* __restrict__ c2, const int* __restrict__ checkp,
                 float* __restrict__ td, float* __restrict__ gxy)
{
    int n = blockIdx.x * TPB + threadIdx.x;
    if (n >= NT_ALL) return;
    float omc = 1.0f - (float)checkp[0];
    const float I[6] = {1.f, 0.f, 0.f, 0.f, 1.f, 0.f};
    float th[6];
    #pragma unroll
    for (int i = 0; i < 6; i++) {
        float v = c2[(size_t)n * 6 + i] * omc + I[i];
        th[i] = v;
        td[(size_t)n * 6 + i] = I[i] - v;
    }
    int S, loc;
    if (n < N0) { S = S0; loc = n; } else { S = S1; loc = n - N0; }
    int SS = S * S;
    int rem = loc % SS;
    int xx = rem / S, yy = rem % S;
    #pragma unroll
    for (int ky = 0; ky < 3; ky++)
        #pragma unroll
        for (int kx = 0; kx < 3; kx++) {
            float bx = (float)(kx - 1), by = (float)(ky - 1);
            gxy[(size_t)n * 18 + ky * 3 + kx]     = th[0] * bx + th[1] * by + th[2] + 1.0f + (float)xx;
            gxy[(size_t)n * 18 + 9 + ky * 3 + kx] = th[3] * bx + th[4] * by + th[5] + 1.0f + (float)yy;
        }
}

// per-batch max + sum(exp) over all 201*388 scores
__global__ __launch_bounds__(TPB)
void softstats_k(const float* __restrict__ sc, float* __restrict__ mx, float* __restrict__ sm)
{
    int b = blockIdx.x, tid = threadIdx.x;
    const float* p = sc + (size_t)b * Oo * LT;
    constexpr int PER = Oo * LT;
    __shared__ float red[TPB];
    float m = -3.4e38f;
    for (int i = tid; i < PER; i += TPB) m = fmaxf(m, p[i]);
    red[tid] = m;
    for (int off = 128; off; off >>= 1) { __syncthreads(); if (tid < off) red[tid] = fmaxf(red[tid], red[tid + off]); }
    __syncthreads();
    m = red[0];
    __syncthreads();
    float s = 0.f;
    for (int i = tid; i < PER; i += TPB) s += expf(p[i] - m);
    red[tid] = s;
    for (int off = 128; off; off >>= 1) { __syncthreads(); if (tid < off) red[tid] += red[tid + off]; }
    __syncthreads();
    if (tid == 0) { mx[b] = m; sm[b] = red[0]; }
}

__global__ __launch_bounds__(TPB)
void lik_k(const float* __restrict__ sc, const float* __restrict__ mx,
           const float* __restrict__ sm, float* __restrict__ lik)
{
    int b = blockIdx.x, o = threadIdx.x;
    if (o >= Oo) return;
    const float* p = sc + ((size_t)b * Oo + o) * LT;
    float m = mx[b];
    float s = 0.f;
    for (int i = 0; i < LT; i++) s += expf(p[i] - m);
    lik[b * Oo + o] = s / sm[b];
}

__global__ __launch_bounds__(TPB)
void box_k(const float* __restrict__ sc, const float* __restrict__ lik,
           const float* __restrict__ mx, const float* __restrict__ sm,
           const float* __restrict__ gxy, const int* __restrict__ imdp,
           float* __restrict__ boxes, float* __restrict__ boxesNT,
           float* __restrict__ regpart)
{
    int b = blockIdx.x, tid = threadIdx.x;
    __shared__ float sv[TPB];
    __shared__ int si[TPB];

    float v = (tid < Oo) ? lik[b * Oo + tid] : -3.4e38f;
    sv[tid] = v; si[tid] = tid;
    for (int off = 128; off; off >>= 1) {
        __syncthreads();
        if (tid < off) {
            float v2 = sv[tid + off]; int i2 = si[tid + off];
            if (v2 > sv[tid] || (v2 == sv[tid] && i2 < si[tid])) { sv[tid] = v2; si[tid] = i2; }
        }
    }
    __syncthreads();
    int pred = si[0];
    __syncthreads();

    const float* p = sc + ((size_t)b * Oo + pred) * LT;
    float b5 = -3.4e38f; int i5 = 1 << 30;
    float b4 = -3.4e38f; int i4 = 1 << 30;
    for (int pos = tid; pos < LT; pos += TPB) {
        float s = p[pos];
        if (pos < L5) { if (s > b5) { b5 = s; i5 = pos; } }
        else { int q = pos - L5; if (s > b4) { b4 = s; i4 = q; } }
    }
    sv[tid] = b5; si[tid] = i5;
    for (int off = 128; off; off >>= 1) {
        __syncthreads();
        if (tid < off) {
            float v2 = sv[tid + off]; int i2 = si[tid + off];
            if (v2 > sv[tid] || (v2 == sv[tid] && i2 < si[tid])) { sv[tid] = v2; si[tid] = i2; }
        }
    }
    __syncthreads();
    float m5 = sv[0]; int d5 = si[0];
    __syncthreads();
    sv[tid] = b4; si[tid] = i4;
    for (int off = 128; off; off >>= 1) {
        __syncthreads();
        if (tid < off) {
            float v2 = sv[tid + off]; int i2 = si[tid + off];
            if (v2 > sv[tid] || (v2 == sv[tid] && i2 < si[tid])) { sv[tid] = v2; si[tid] = i2; }
        }
    }
    __syncthreads();
    float m4 = sv[0]; int d4 = si[0];

    if (tid == 0) {
        float m = mx[b], s = sm[b];
        float conf5 = expf(m5 - m) / s;
        float conf4 = expf(m4 - m) / s;
        float imd = (float)imdp[0];
        float lo = 0.f, hi = imd - 1.f;

        int xx5 = d5 % S0, yy5 = d5 / S0;
        int n5 = b * (S0 * S0) + xx5 * S0 + yy5;
        const float* g = gxy + (size_t)n5 * 18;
        float txm = 1e30f, txM = -1e30f, tym = 1e30f, tyM = -1e30f;
        for (int j = 0; j < 9; j++) {
            float tx = g[j] / 9.f, ty = g[9 + j] / 9.f;
            txm = fminf(txm, tx); txM = fmaxf(txM, tx);
            tym = fminf(tym, ty); tyM = fmaxf(tyM, ty);
        }
        float box5[5] = { clampf(txm * imd, lo, hi), clampf(tym * imd, lo, hi),
                          clampf(txM * imd, lo, hi), clampf(tyM * imd, lo, hi), conf5 };
        float nt5[5]  = { clampf((float)xx5 / 9.f * imd, lo, hi), clampf((float)yy5 / 9.f * imd, lo, hi),
                          clampf((float)(xx5 + 2) / 9.f * imd, lo, hi), clampf((float)(yy5 + 2) / 9.f * imd, lo, hi), conf5 };

        int xx4 = d4 % S1, yy4 = d4 / S1;
        int n4 = N0 + b * (S1 * S1) + xx4 * S1 + yy4;
        const float* g4 = gxy + (size_t)n4 * 18;
        float txm4 = 1e30f, txM4 = -1e30f, tym4 = 1e30f, tyM4 = -1e30f;
        for (int j = 0; j < 9; j++) {
            float tx = g4[j] / 19.f, ty = g4[9 + j] / 19.f;
            txm4 = fminf(txm4, tx); txM4 = fmaxf(txM4, tx);
            tym4 = fminf(tym4, ty); tyM4 = fmaxf(tyM4, ty);
        }
        float box4[5] = { clampf(txm4 * imd, lo, hi), clampf(tym4 * imd, lo, hi),
                          clampf(txM4 * imd, lo, hi), clampf(tyM4 * imd, lo, hi), conf4 };
        float nt4[5]  = { clampf((float)xx4 / 19.f * imd, lo, hi), clampf((float)yy4 / 19.f * imd, lo, hi),
                          clampf((float)(xx4 + 2) / 19.f * imd, lo, hi), clampf((float)(yy4 + 2) / 19.f * imd, lo, hi), conf4 };

        int mi = (conf4 > conf5) ? 1 : 0;
        for (int i = 0; i < 5; i++) {
            boxes[b * 5 + i]   = mi ? box4[i] : box5[i];
            boxesNT[b * 5 + i] = mi ? nt4[i] : nt5[i];
        }
        regpart[b] = fmaxf(conf4 - conf5, 0.f);
    }
}

__global__ void reg_k(const float* __restrict__ regpart, float* __restrict__ outreg)
{
    if (threadIdx.x == 0) {
        float s = 0.f;
        for (int b = 0; b < Bb; b++) s += regpart[b];
        outreg[0] = s;
    }
}

__global__ void sentinel_k(float* out, int n)
{
    int i = blockIdx.x * 256 + threadIdx.x;
    if (i < n) out[i] = 12345.0f;
}

extern "C" void kernel_launch(void* const* d_in, const int* in_sizes, int n_in,
                              void* d_out, int out_size, void* d_ws, size_t ws_size,
                              hipStream_t stream)
{
    const float* x0 = (const float*)d_in[0];
    const float* x1 = (const float*)d_in[1];
    const float* w0 = (const float*)d_in[2];
    const float* b0 = (const float*)d_in[3];
    const float* w1 = (const float*)d_in[4];
    const float* cw = (const float*)d_in[5];
    const float* cb = (const float*)d_in[6];
    const float* lw = (const float*)d_in[7];
    const float* lb = (const float*)d_in[8];
    const int* checkp = (const int*)d_in[9];
    const int* imdp   = (const int*)d_in[10];

    if (ws_size < B_END) {
        sentinel_k<<<dim3((out_size + 255) / 256), dim3(256), 0, stream>>>((float*)d_out, out_size);
        return;
    }

    char* wsb = (char*)d_ws;
    short* cwh = (short*)(wsb + B_CWH);
    short* cwl = (short*)(wsb + B_CWL);
    short* w0h = (short*)(wsb + B_W0H);
    short* w0l = (short*)(wsb + B_W0L);
    float* gxy = (float*)(wsb + B_GXY);
    short* lwh = (short*)(wsb + B_LWH);
    short* lwl = (short*)(wsb + B_LWL);
    short* fH  = (short*)(wsb + B_FEATH);
    short* fL  = (short*)(wsb + B_FEATL);
    float* mx  = (float*)(wsb + B_MX);
    float* sm  = (float*)(wsb + B_SM);
    float* rp  = (float*)(wsb + B_RP);
    float* sc  = (float*)(wsb + B_SC);
    float* c2  = (float*)(wsb + B_C2);
    float* h0  = (float*)(wsb + B_H0);
    float* h1  = (float*)(wsb + B_H1);

    float* out   = (float*)d_out;
    float* o_lik = out + O_LIK;
    float* o_box = out + O_BOX;
    float* o_nt  = out + O_NT;
    float* o_td  = out + O_TD;
    float* o_reg = out + O_REG;

    dim3 blk(TPB);

    // weight splits (w0/cw K-permuted; lw plain)
    splitp_k<<<dim3((SZ_W0 + TPB - 1) / TPB), blk, 0, stream>>>(w0, w0h, w0l, Cc);
    splitp_k<<<dim3((SZ_CW + TPB - 1) / TPB), blk, 0, stream>>>(cw, cwh, cwl, Ff);
    split_k <<<dim3((SZ_LW + TPB - 1) / TPB), blk, 0, stream>>>(lw, lwh, lwl, (int)SZ_LW);

    // conv1 (+bias, relu) -> h fp32, both scales
    mgemm<0, H0, 1, Bb * H0 * H0, Cc, KC, 0><<<dim3(25, 2), blk, 0, stream>>>(
        x0, nullptr, nullptr, nullptr, w0h, w0l, b0, h0, nullptr, nullptr);
    mgemm<0, H1, 1, Bb * H1 * H1, Cc, KC, 0><<<dim3(100, 2), blk, 0, stream>>>(
        x1, nullptr, nullptr, nullptr, w0h, w0l, b0, h1, nullptr, nullptr);

    // conv2 (6 ch) -> c2
    conv2_k<<<dim3(NT_ALL / 32), blk, 0, stream>>>(h0, h1, w1, c2);

    // theta, theta_diff, sampling coords
    theta_aux_k<<<dim3((NT_ALL + TPB - 1) / TPB), blk, 0, stream>>>(c2, checkp, o_td, gxy);

    // fused bilinear-sample GEMM -> feat hi/lo (clobbers h: dead)
    mgemm<2, H0, S0, N0, Ff, KC, 0><<<dim3(16, 8), blk, 0, stream>>>(
        x0, nullptr, nullptr, gxy, cwh, cwl, cb, nullptr, fH, fL);
    mgemm<2, H1, S1, N1, Ff, KC, 0><<<dim3(81, 8), blk, 0, stream>>>(
        x1, nullptr, nullptr, gxy + (size_t)N0 * 18, cwh, cwl, cb,
        nullptr, fH + (size_t)N0 * Ff, fL + (size_t)N0 * Ff);

    // feat -> scores scatter (sc clobbers cw splits: dead)
    mgemm<3, 1, S0, N0, Oo, Ff, 0><<<dim3(16, 2), blk, 0, stream>>>(
        nullptr, fH, fL, nullptr, lwh, lwl, lb, sc, nullptr, nullptr);
    mgemm<3, 1, S1, N1, Oo, Ff, L5><<<dim3(81, 2), blk, 0, stream>>>(
        nullptr, fH + (size_t)N0 * Ff, fL + (size_t)N0 * Ff, nullptr, lwh, lwl, lb,
        sc, nullptr, nullptr);

    // softmax stats, likelihood, boxes, reg
    softstats_k<<<dim3(Bb), blk, 0, stream>>>(sc, mx, sm);
    lik_k<<<dim3(Bb), blk, 0, stream>>>(sc, mx, sm, o_lik);
    box_k<<<dim3(Bb), blk, 0, stream>>>(sc, o_lik, mx, sm, gxy, imdp, o_box, o_nt, rp);
    reg_k<<<dim3(1), dim3(64), 0, stream>>>(rp, o_reg);
}

// Round 3
// 1837.464 us; speedup vs baseline: 2.2088x; 1.0177x over previous
//
#include <hip/hip_runtime.h>
#include <cmath>

#define TPB 256

// ---- problem constants (fixed by setup_inputs) ----
constexpr int Bb = 32, Cc = 256, Ff = 1024, Oo = 201;
constexpr int H0 = 10, S0 = 8,  N0 = Bb * S0 * S0;   // 2048
constexpr int H1 = 20, S1 = 18, N1 = Bb * S1 * S1;   // 10368
constexpr int NT_ALL = N0 + N1;                      // 12416
constexpr int KC = Cc * 9;                           // 2304
constexpr int L5 = S0 * S0;                          // 64
constexpr int L4 = S1 * S1;                          // 324
constexpr int LT = L5 + L4;                          // 388

// ---- element counts ----
constexpr size_t SZ_CW = (size_t)Ff * KC;       // 2,359,296
constexpr size_t SZ_W0 = (size_t)Cc * KC;       // 589,824
constexpr size_t SZ_LW = (size_t)Oo * Ff;       // 205,824
constexpr size_t NFEAT = (size_t)NT_ALL * Ff;   // 12,713,984

// ---- workspace byte offsets (time-disjoint aliasing) ----
constexpr size_t B_CWH = 0;
constexpr size_t B_CWL = B_CWH + SZ_CW * 2;            // 4,718,592
constexpr size_t B_W0H = B_CWL + SZ_CW * 2;            // 9,437,184
constexpr size_t B_W0L = B_W0H + SZ_W0 * 2;            // 10,616,832
constexpr size_t B_GXY = B_W0L + SZ_W0 * 2;            // 11,796,480
constexpr size_t B_LWH = B_GXY + (size_t)NT_ALL * 18 * 4; // 12,690,432
constexpr size_t B_LWL = B_LWH + SZ_LW * 2;            // 13,102,080
constexpr size_t B_FEATH = B_LWL + SZ_LW * 2;          // 13,513,728
constexpr size_t B_FEATL = B_FEATH + NFEAT * 2;        // 38,941,696
constexpr size_t B_MX  = B_FEATL + NFEAT * 2;          // 64,369,664
constexpr size_t B_SM  = B_MX + 128;
constexpr size_t B_RP  = B_SM + 128;
constexpr size_t B_END = B_RP + 128;                   // ~64.4 MB
// aliases (disjoint lifetimes):
constexpr size_t B_SC  = B_CWH;    // sc over dead cw splits
constexpr size_t B_C2  = B_W0H;    // c2 over dead w0 splits
constexpr size_t B_H0  = B_FEATH;  // h0 over not-yet-written feat
constexpr size_t B_H1  = B_H0 + (size_t)Bb * Cc * H0 * H0 * 4;

// ---- output layout (floats) ----
constexpr size_t O_LIK = 0;
constexpr size_t O_BOX = O_LIK + Bb * Oo;
constexpr size_t O_NT  = O_BOX + Bb * 5;
constexpr size_t O_TD  = O_NT + Bb * 5;
constexpr size_t O_REG = O_TD + (size_t)NT_ALL * 6;

typedef __attribute__((ext_vector_type(8))) short bf16x8;
typedef __attribute__((ext_vector_type(4))) float f32x4;

__device__ __forceinline__ short f2bf(float f) {
    unsigned u = __builtin_bit_cast(unsigned, f);
    u += 0x7fffu + ((u >> 16) & 1u);
    return (short)(u >> 16);
}
__device__ __forceinline__ float bf2f(short s) {
    unsigned u = ((unsigned)(unsigned short)s) << 16;
    return __builtin_bit_cast(float, u);
}
__device__ __forceinline__ float clampf(float x, float lo, float hi) {
    return fminf(fmaxf(x, lo), hi);
}

// =====================================================================
// split kernels: fp32 -> (hi, lo) bf16.  splitp also permutes K:
// src k = c*9 + t  ->  dst k' = t*256 + c   (per row of length 2304)
// =====================================================================
__global__ __launch_bounds__(TPB)
void splitp_k(const float* __restrict__ src, short* __restrict__ hi,
              short* __restrict__ lo, int nrows)
{
    int idx = blockIdx.x * TPB + threadIdx.x;
    int total = nrows * KC;
    if (idx >= total) return;
    int row = idx / KC, k = idx - row * KC;
    int c = k / 9, t = k - c * 9;
    float v = src[idx];
    short hs = f2bf(v);
    size_t dst = (size_t)row * KC + t * 256 + c;
    hi[dst] = hs;
    lo[dst] = f2bf(v - bf2f(hs));
}

__global__ __launch_bounds__(TPB)
void split_k(const float* __restrict__ src, short* __restrict__ hi,
             short* __restrict__ lo, int n)
{
    int idx = blockIdx.x * TPB + threadIdx.x;
    if (idx >= n) return;
    float v = src[idx];
    short hs = f2bf(v);
    hi[idx] = hs;
    lo[idx] = f2bf(v - bf2f(hs));
}

// =====================================================================
// Split-bf16 MFMA GEMM: out(MxN) = A(MxK) * Bw(NxK)^T (+bias, act)
// Block 128x128, BK=32, 4 waves (64x64 each), mfma_f32_16x16x32_bf16,
// 3 MFMAs per tile pair (hi*hi + lo*hi + hi*lo).
// GRID: dim3(nN, nM) -- n FASTEST so wgid = m*nN + n; with nN | 8 each
// XCD (wgid%8) is pinned to ONE B-tile (L2-resident) and walks m
// sequentially (A-row / x-plane L2 locality).
// =====================================================================
template<int MODE, int H, int S, int M, int N, int KD, int POS>
__global__ __launch_bounds__(TPB, 2)
void mgemm(const float* __restrict__ Asrc,
           const short* __restrict__ AsrcH, const short* __restrict__ AsrcL,
           const float* __restrict__ gxy,
           const short* __restrict__ Bh, const short* __restrict__ Bl,
           const float* __restrict__ bias,
           float* __restrict__ outF, short* __restrict__ outH, short* __restrict__ outL)
{
    __shared__ short As[2][4][128][8];   // [hi/lo][kgrp][m][e] : 16KB
    __shared__ short Bs[2][4][128][8];   // 16KB
    const int tid = threadIdx.x;
    const int lane = tid & 63;
    const int wid = tid >> 6;
    const int wm = (wid >> 1) * 64, wn = (wid & 1) * 64;
    const int ml = tid & 127, kg0 = tid >> 7;
    const int bm = blockIdx.y * 128, bn = blockIdx.x * 128;   // n fastest

    f32x4 acc[4][4];
    #pragma unroll
    for (int i = 0; i < 4; i++)
        #pragma unroll
        for (int j = 0; j < 4; j++)
            acc[i][j] = (f32x4){0.f, 0.f, 0.f, 0.f};

    const int mG = bm + ml;
    int bA = 0, yA = 0, xA = 0;
    if constexpr (MODE == 0) {
        bA = mG / (H * H); int rem = mG - bA * (H * H);
        yA = rem / H; xA = rem - yA * H;
    } else if constexpr (MODE == 2) {
        bA = mG / (S * S);
    }
    const int nG = bn + ml;

    // hoisted per-tap state (MODE 0 / MODE 2); tap changes every 8 kb-steps
    int tcur = -1;
    bool okA = false;
    const float* bpA = nullptr;           // MODE 0 tap-adjusted base
    const float* bbase = nullptr;         // MODE 2 batch base
    float w00 = 0, w01 = 0, w10 = 0, w11 = 0;
    int o00 = 0, o01 = 0, o10 = 0, o11 = 0;
    if constexpr (MODE == 2) bbase = Asrc + (size_t)bA * Cc * (H * H);

    for (int kb = 0; kb < KD; kb += 32) {
        // ---------- stage A ----------
        if constexpr (MODE == 0) {
            const int t = kb >> 8;
            if (t != tcur) {
                tcur = t;
                const int ky = t / 3 - 1, kx = t - (t / 3) * 3 - 1;
                const int yy = yA + ky, xx = xA + kx;
                okA = (yy >= 0 && yy < H && xx >= 0 && xx < H);
                bpA = Asrc + (size_t)bA * Cc * (H * H) + yy * H + xx;
            }
            const int c0 = kb & 255;
            #pragma unroll
            for (int hh = 0; hh < 2; hh++) {
                int kg = kg0 + 2 * hh;
                bf16x8 hv, lv;
                #pragma unroll
                for (int e = 0; e < 8; e++) {
                    int c = c0 + kg * 8 + e;
                    float v = okA ? bpA[(size_t)c * (H * H)] : 0.f;
                    short hs = f2bf(v); hv[e] = hs;
                    lv[e] = f2bf(v - bf2f(hs));
                }
                *(bf16x8*)&As[0][kg][ml][0] = hv;
                *(bf16x8*)&As[1][kg][ml][0] = lv;
            }
        } else if constexpr (MODE == 2) {
            const int j = kb >> 8;
            if (j != tcur) {
                tcur = j;
                const float gx = gxy[(size_t)mG * 18 + j];
                const float gy = gxy[(size_t)mG * 18 + 9 + j];
                const float xf = floorf(gx), yf = floorf(gy);
                const float wx = gx - xf, wy = gy - yf;
                const int ix = (int)xf, iy = (int)yf;
                const int cx0 = min(max(ix, 0), H - 1), cx1 = min(max(ix + 1, 0), H - 1);
                const int cy0 = min(max(iy, 0), H - 1), cy1 = min(max(iy + 1, 0), H - 1);
                const float vx0 = (ix >= 0 && ix < H) ? 1.f : 0.f;
                const float vx1 = (ix + 1 >= 0 && ix + 1 < H) ? 1.f : 0.f;
                const float vy0 = (iy >= 0 && iy < H) ? 1.f : 0.f;
                const float vy1 = (iy + 1 >= 0 && iy + 1 < H) ? 1.f : 0.f;
                w00 = (1.f - wy) * (1.f - wx) * vy0 * vx0;
                w01 = (1.f - wy) * wx * vy0 * vx1;
                w10 = wy * (1.f - wx) * vy1 * vx0;
                w11 = wy * wx * vy1 * vx1;
                o00 = cy0 * H + cx0; o01 = cy0 * H + cx1;
                o10 = cy1 * H + cx0; o11 = cy1 * H + cx1;
            }
            const int c0 = kb & 255;
            const float* bp = bbase + (size_t)c0 * (H * H);
            #pragma unroll
            for (int hh = 0; hh < 2; hh++) {
                int kg = kg0 + 2 * hh;
                bf16x8 hv, lv;
                #pragma unroll
                for (int e = 0; e < 8; e++) {
                    const float* cp = bp + (size_t)(kg * 8 + e) * (H * H);
                    float v = cp[o00] * w00 + cp[o01] * w01 + cp[o10] * w10 + cp[o11] * w11;
                    short hs = f2bf(v); hv[e] = hs;
                    lv[e] = f2bf(v - bf2f(hs));
                }
                *(bf16x8*)&As[0][kg][ml][0] = hv;
                *(bf16x8*)&As[1][kg][ml][0] = lv;
            }
        } else { // MODE 3
            #pragma unroll
            for (int hh = 0; hh < 2; hh++) {
                int kg = kg0 + 2 * hh;
                *(bf16x8*)&As[0][kg][ml][0] = *(const bf16x8*)(AsrcH + (size_t)mG * KD + kb + kg * 8);
                *(bf16x8*)&As[1][kg][ml][0] = *(const bf16x8*)(AsrcL + (size_t)mG * KD + kb + kg * 8);
            }
        }
        // ---------- stage B ----------
        #pragma unroll
        for (int hh = 0; hh < 2; hh++) {
            int kg = kg0 + 2 * hh;
            bf16x8 hv = {}, lv = {};
            if (nG < N) {
                hv = *(const bf16x8*)(Bh + (size_t)nG * KD + kb + kg * 8);
                lv = *(const bf16x8*)(Bl + (size_t)nG * KD + kb + kg * 8);
            }
            *(bf16x8*)&Bs[0][kg][ml][0] = hv;
            *(bf16x8*)&Bs[1][kg][ml][0] = lv;
        }
        __syncthreads();
        // ---------- compute ----------
        {
            const int kq = lane >> 4, r = lane & 15;
            bf16x8 ah[4], al[4], bhf[4], blf[4];
            #pragma unroll
            for (int i = 0; i < 4; i++) {
                ah[i]  = *(const bf16x8*)&As[0][kq][wm + i * 16 + r][0];
                al[i]  = *(const bf16x8*)&As[1][kq][wm + i * 16 + r][0];
                bhf[i] = *(const bf16x8*)&Bs[0][kq][wn + i * 16 + r][0];
                blf[i] = *(const bf16x8*)&Bs[1][kq][wn + i * 16 + r][0];
            }
            #pragma unroll
            for (int i = 0; i < 4; i++)
                #pragma unroll
                for (int j = 0; j < 4; j++) {
                    acc[i][j] = __builtin_amdgcn_mfma_f32_16x16x32_bf16(ah[i], bhf[j], acc[i][j], 0, 0, 0);
                    acc[i][j] = __builtin_amdgcn_mfma_f32_16x16x32_bf16(al[i], bhf[j], acc[i][j], 0, 0, 0);
                    acc[i][j] = __builtin_amdgcn_mfma_f32_16x16x32_bf16(ah[i], blf[j], acc[i][j], 0, 0, 0);
                }
        }
        __syncthreads();
    }

    // ---------- epilogue ----------
    const int kq = lane >> 4, rr = lane & 15;
    #pragma unroll
    for (int i = 0; i < 4; i++) {
        #pragma unroll
        for (int r = 0; r < 4; r++) {
            const int gm = bm + wm + i * 16 + kq * 4 + r;
            #pragma unroll
            for (int j = 0; j < 4; j++) {
                const int gn = bn + wn + j * 16 + rr;
                float v = acc[i][j][r];
                if constexpr (MODE == 0) {
                    int bq = gm / (H * H); int rem = gm - bq * (H * H);
                    int yq = rem / H; int xq = rem - yq * H;
                    outF[(((size_t)bq * Cc + gn) * H + yq) * H + xq] = fmaxf(v + bias[gn], 0.f);
                } else if constexpr (MODE == 2) {
                    float q = fmaxf(v + bias[gn], 0.f);
                    short hs = f2bf(q);
                    outH[(size_t)gm * Ff + gn] = hs;
                    outL[(size_t)gm * Ff + gn] = f2bf(q - bf2f(hs));
                } else {
                    if (gn < N) {
                        int bq = gm / (S * S); int rem = gm - bq * (S * S);
                        int xq = rem / S; int yq = rem - xq * S;
                        outF[((size_t)bq * Oo + gn) * LT + (yq * S + xq + POS)] = v + bias[gn];
                    }
                }
            }
        }
    }
}

// =====================================================================
// conv2: N=6 tiny conv. 32 rows/block, 8 ci-groups, w1 in LDS.
// =====================================================================
__global__ __launch_bounds__(TPB)
void conv2_k(const float* __restrict__ h0, const float* __restrict__ h1,
             const float* __restrict__ w1, float* __restrict__ c2)
{
    __shared__ float wl[6][KC];       // 55.3 KB
    __shared__ float part[8][32][6];  // 6 KB
    const int tid = threadIdx.x;
    for (int i = tid; i < 6 * KC; i += TPB) wl[i / KC][i - (i / KC) * KC] = w1[i];
    __syncthreads();
    const int row = blockIdx.x * 32 + (tid & 31);
    const int cig = tid >> 5;
    const float* hsrc; int H, S, loc;
    if (row < N0) { hsrc = h0; H = H0; S = S0; loc = row; }
    else          { hsrc = h1; H = H1; S = S1; loc = row - N0; }
    int SS = S * S;
    int b = loc / SS; int rem = loc - b * SS;
    int xq = rem / S; int yq = rem - xq * S;
    float acc[6] = {};
    for (int ci = cig * 32; ci < cig * 32 + 32; ci++) {
        const float* hp = hsrc + ((size_t)(b * Cc + ci) * H + yq) * H + xq;
        #pragma unroll
        for (int ky = 0; ky < 3; ky++)
            #pragma unroll
            for (int kx = 0; kx < 3; kx++) {
                float a = hp[ky * H + kx];
                int kk = ci * 9 + ky * 3 + kx;
                #pragma unroll
                for (int n = 0; n < 6; n++) acc[n] = fmaf(a, wl[n][kk], acc[n]);
            }
    }
    #pragma unroll
    for (int n = 0; n < 6; n++) part[cig][tid & 31][n] = acc[n];
    __syncthreads();
    if (cig == 0) {
        #pragma unroll
        for (int n = 0; n < 6; n++) {
            float s = 0.f;
            for (int g = 0; g < 8; g++) s += part[g][tid & 31][n];
            c2[(size_t)row * 6 + n] = s;
        }
    }
}

// ====================================================================
// theta / theta_diff / sampling-coordinate kernel  (verified round 1)
// ====================================================================
__global__ __launch_bounds__(TPB)
void theta_aux_k(const float* __restrict__ c2, const int* __restrict__ checkp,
                 float* __restrict__ td, float* __restrict__ gxy)
{
    int n = blockIdx.x * TPB + threadIdx.x;
    if (n >= NT_ALL) return;
    float omc = 1.0f - (float)checkp[0];
    const float I[6] = {1.f, 0.f, 0.f, 0.f, 1.f, 0.f};
    float th[6];
    #pragma unroll
    for (int i = 0; i < 6; i++) {
        float v = c2[(size_t)n * 6 + i] * omc + I[i];
        th[i] = v;
        td[(size_t)n * 6 + i] = I[i] - v;
    }
    int S, loc;
    if (n < N0) { S = S0; loc = n; } else { S = S1; loc = n - N0; }
    int SS = S * S;
    int rem = loc % SS;
    int xx = rem / S, yy = rem % S;
    #pragma unroll
    for (int ky = 0; ky < 3; ky++)
        #pragma unroll
        for (int kx = 0; kx < 3; kx++) {
            float bx = (float)(kx - 1), by = (float)(ky - 1);
            gxy[(size_t)n * 18 + ky * 3 + kx]     = th[0] * bx + th[1] * by + th[2] + 1.0f + (float)xx;
            gxy[(size_t)n * 18 + 9 + ky * 3 + kx] = th[3] * bx + th[4] * by + th[5] + 1.0f + (float)yy;
        }
}

// per-batch max + sum(exp) over all 201*388 scores
__global__ __launch_bounds__(TPB)
void softstats_k(const float* __restrict__ sc, float* __restrict__ mx, float* __restrict__ sm)
{
    int b = blockIdx.x, tid = threadIdx.x;
    const float* p = sc + (size_t)b * Oo * LT;
    constexpr int PER = Oo * LT;
    __shared__ float red[TPB];
    float m = -3.4e38f;
    for (int i = tid; i < PER; i += TPB) m = fmaxf(m, p[i]);
    red[tid] = m;
    for (int off = 128; off; off >>= 1) { __syncthreads(); if (tid < off) red[tid] = fmaxf(red[tid], red[tid + off]); }
    __syncthreads();
    m = red[0];
    __syncthreads();
    float s = 0.f;
    for (int i = tid; i < PER; i += TPB) s += expf(p[i] - m);
    red[tid] = s;
    for (int off = 128; off; off >>= 1) { __syncthreads(); if (tid < off) red[tid] += red[tid + off]; }
    __syncthreads();
    if (tid == 0) { mx[b] = m; sm[b] = red[0]; }
}

__global__ __launch_bounds__(TPB)
void lik_k(const float* __restrict__ sc, const float* __restrict__ mx,
           const float* __restrict__ sm, float* __restrict__ lik)
{
    int b = blockIdx.x, o = threadIdx.x;
    if (o >= Oo) return;
    const float* p = sc + ((size_t)b * Oo + o) * LT;
    float m = mx[b];
    float s = 0.f;
    for (int i = 0; i < LT; i++) s += expf(p[i] - m);
    lik[b * Oo + o] = s / sm[b];
}

__global__ __launch_bounds__(TPB)
void box_k(const float* __restrict__ sc, const float* __restrict__ lik,
           const float* __restrict__ mx, const float* __restrict__ sm,
           const float* __restrict__ gxy, const int* __restrict__ imdp,
           float* __restrict__ boxes, float* __restrict__ boxesNT,
           float* __restrict__ regpart)
{
    int b = blockIdx.x, tid = threadIdx.x;
    __shared__ float sv[TPB];
    __shared__ int si[TPB];

    float v = (tid < Oo) ? lik[b * Oo + tid] : -3.4e38f;
    sv[tid] = v; si[tid] = tid;
    for (int off = 128; off; off >>= 1) {
        __syncthreads();
        if (tid < off) {
            float v2 = sv[tid + off]; int i2 = si[tid + off];
            if (v2 > sv[tid] || (v2 == sv[tid] && i2 < si[tid])) { sv[tid] = v2; si[tid] = i2; }
        }
    }
    __syncthreads();
    int pred = si[0];
    __syncthreads();

    const float* p = sc + ((size_t)b * Oo + pred) * LT;
    float b5 = -3.4e38f; int i5 = 1 << 30;
    float b4 = -3.4e38f; int i4 = 1 << 30;
    for (int pos = tid; pos < LT; pos += TPB) {
        float s = p[pos];
        if (pos < L5) { if (s > b5) { b5 = s; i5 = pos; } }
        else { int q = pos - L5; if (s > b4) { b4 = s; i4 = q; } }
    }
    sv[tid] = b5; si[tid] = i5;
    for (int off = 128; off; off >>= 1) {
        __syncthreads();
        if (tid < off) {
            float v2 = sv[tid + off]; int i2 = si[tid + off];
            if (v2 > sv[tid] || (v2 == sv[tid] && i2 < si[tid])) { sv[tid] = v2; si[tid] = i2; }
        }
    }
    __syncthreads();
    float m5 = sv[0]; int d5 = si[0];
    __syncthreads();
    sv[tid] = b4; si[tid] = i4;
    for (int off = 128; off; off >>= 1) {
        __syncthreads();
        if (tid < off) {
            float v2 = sv[tid + off]; int i2 = si[tid + off];
            if (v2 > sv[tid] || (v2 == sv[tid] && i2 < si[tid])) { sv[tid] = v2; si[tid] = i2; }
        }
    }
    __syncthreads();
    float m4 = sv[0]; int d4 = si[0];

    if (tid == 0) {
        float m = mx[b], s = sm[b];
        float conf5 = expf(m5 - m) / s;
        float conf4 = expf(m4 - m) / s;
        float imd = (float)imdp[0];
        float lo = 0.f, hi = imd - 1.f;

        int xx5 = d5 % S0, yy5 = d5 / S0;
        int n5 = b * (S0 * S0) + xx5 * S0 + yy5;
        const float* g = gxy + (size_t)n5 * 18;
        float txm = 1e30f, txM = -1e30f, tym = 1e30f, tyM = -1e30f;
        for (int j = 0; j < 9; j++) {
            float tx = g[j] / 9.f, ty = g[9 + j] / 9.f;
            txm = fminf(txm, tx); txM = fmaxf(txM, tx);
            tym = fminf(tym, ty); tyM = fmaxf(tyM, ty);
        }
        float box5[5] = { clampf(txm * imd, lo, hi), clampf(tym * imd, lo, hi),
                          clampf(txM * imd, lo, hi), clampf(tyM * imd, lo, hi), conf5 };
        float nt5[5]  = { clampf((float)xx5 / 9.f * imd, lo, hi), clampf((float)yy5 / 9.f * imd, lo, hi),
                          clampf((float)(xx5 + 2) / 9.f * imd, lo, hi), clampf((float)(yy5 + 2) / 9.f * imd, lo, hi), conf5 };

        int xx4 = d4 % S1, yy4 = d4 / S1;
        int n4 = N0 + b * (S1 * S1) + xx4 * S1 + yy4;
        const float* g4 = gxy + (size_t)n4 * 18;
        float txm4 = 1e30f, txM4 = -1e30f, tym4 = 1e30f, tyM4 = -1e30f;
        for (int j = 0; j < 9; j++) {
            float tx = g4[j] / 19.f, ty = g4[9 + j] / 19.f;
            txm4 = fminf(txm4, tx); txM4 = fmaxf(txM4, tx);
            tym4 = fminf(tym4, ty); tyM4 = fmaxf(tyM4, ty);
        }
        float box4[5] = { clampf(txm4 * imd, lo, hi), clampf(tym4 * imd, lo, hi),
                          clampf(txM4 * imd, lo, hi), clampf(tyM4 * imd, lo, hi), conf4 };
        float nt4[5]  = { clampf((float)xx4 / 19.f * imd, lo, hi), clampf((float)yy4 / 19.f * imd, lo, hi),
                          clampf((float)(xx4 + 2) / 19.f * imd, lo, hi), clampf((float)(yy4 + 2) / 19.f * imd, lo, hi), conf4 };

        int mi = (conf4 > conf5) ? 1 : 0;
        for (int i = 0; i < 5; i++) {
            boxes[b * 5 + i]   = mi ? box4[i] : box5[i];
            boxesNT[b * 5 + i] = mi ? nt4[i] : nt5[i];
        }
        regpart[b] = fmaxf(conf4 - conf5, 0.f);
    }
}

__global__ void reg_k(const float* __restrict__ regpart, float* __restrict__ outreg)
{
    if (threadIdx.x == 0) {
        float s = 0.f;
        for (int b = 0; b < Bb; b++) s += regpart[b];
        outreg[0] = s;
    }
}

__global__ void sentinel_k(float* out, int n)
{
    int i = blockIdx.x * 256 + threadIdx.x;
    if (i < n) out[i] = 12345.0f;
}

extern "C" void kernel_launch(void* const* d_in, const int* in_sizes, int n_in,
                              void* d_out, int out_size, void* d_ws, size_t ws_size,
                              hipStream_t stream)
{
    const float* x0 = (const float*)d_in[0];
    const float* x1 = (const float*)d_in[1];
    const float* w0 = (const float*)d_in[2];
    const float* b0 = (const float*)d_in[3];
    const float* w1 = (const float*)d_in[4];
    const float* cw = (const float*)d_in[5];
    const float* cb = (const float*)d_in[6];
    const float* lw = (const float*)d_in[7];
    const float* lb = (const float*)d_in[8];
    const int* checkp = (const int*)d_in[9];
    const int* imdp   = (const int*)d_in[10];

    if (ws_size < B_END) {
        sentinel_k<<<dim3((out_size + 255) / 256), dim3(256), 0, stream>>>((float*)d_out, out_size);
        return;
    }

    char* wsb = (char*)d_ws;
    short* cwh = (short*)(wsb + B_CWH);
    short* cwl = (short*)(wsb + B_CWL);
    short* w0h = (short*)(wsb + B_W0H);
    short* w0l = (short*)(wsb + B_W0L);
    float* gxy = (float*)(wsb + B_GXY);
    short* lwh = (short*)(wsb + B_LWH);
    short* lwl = (short*)(wsb + B_LWL);
    short* fH  = (short*)(wsb + B_FEATH);
    short* fL  = (short*)(wsb + B_FEATL);
    float* mx  = (float*)(wsb + B_MX);
    float* sm  = (float*)(wsb + B_SM);
    float* rp  = (float*)(wsb + B_RP);
    float* sc  = (float*)(wsb + B_SC);
    float* c2  = (float*)(wsb + B_C2);
    float* h0  = (float*)(wsb + B_H0);
    float* h1  = (float*)(wsb + B_H1);

    float* out   = (float*)d_out;
    float* o_lik = out + O_LIK;
    float* o_box = out + O_BOX;
    float* o_nt  = out + O_NT;
    float* o_td  = out + O_TD;
    float* o_reg = out + O_REG;

    dim3 blk(TPB);

    // weight splits (w0/cw K-permuted; lw plain)
    splitp_k<<<dim3((SZ_W0 + TPB - 1) / TPB), blk, 0, stream>>>(w0, w0h, w0l, Cc);
    splitp_k<<<dim3((SZ_CW + TPB - 1) / TPB), blk, 0, stream>>>(cw, cwh, cwl, Ff);
    split_k <<<dim3((SZ_LW + TPB - 1) / TPB), blk, 0, stream>>>(lw, lwh, lwl, (int)SZ_LW);

    // conv1 (+bias, relu) -> h fp32, both scales   [grid = (nN, nM)]
    mgemm<0, H0, 1, Bb * H0 * H0, Cc, KC, 0><<<dim3(2, 25), blk, 0, stream>>>(
        x0, nullptr, nullptr, nullptr, w0h, w0l, b0, h0, nullptr, nullptr);
    mgemm<0, H1, 1, Bb * H1 * H1, Cc, KC, 0><<<dim3(2, 100), blk, 0, stream>>>(
        x1, nullptr, nullptr, nullptr, w0h, w0l, b0, h1, nullptr, nullptr);

    // conv2 (6 ch) -> c2
    conv2_k<<<dim3(NT_ALL / 32), blk, 0, stream>>>(h0, h1, w1, c2);

    // theta, theta_diff, sampling coords
    theta_aux_k<<<dim3((NT_ALL + TPB - 1) / TPB), blk, 0, stream>>>(c2, checkp, o_td, gxy);

    // fused bilinear-sample GEMM -> feat hi/lo (clobbers h: dead)
    mgemm<2, H0, S0, N0, Ff, KC, 0><<<dim3(8, 16), blk, 0, stream>>>(
        x0, nullptr, nullptr, gxy, cwh, cwl, cb, nullptr, fH, fL);
    mgemm<2, H1, S1, N1, Ff, KC, 0><<<dim3(8, 81), blk, 0, stream>>>(
        x1, nullptr, nullptr, gxy + (size_t)N0 * 18, cwh, cwl, cb,
        nullptr, fH + (size_t)N0 * Ff, fL + (size_t)N0 * Ff);

    // feat -> scores scatter (sc clobbers cw splits: dead)
    mgemm<3, 1, S0, N0, Oo, Ff, 0><<<dim3(2, 16), blk, 0, stream>>>(
        nullptr, fH, fL, nullptr, lwh, lwl, lb, sc, nullptr, nullptr);
    mgemm<3, 1, S1, N1, Oo, Ff, L5><<<dim3(2, 81), blk, 0, stream>>>(
        nullptr, fH + (size_t)N0 * Ff, fL + (size_t)N0 * Ff, nullptr, lwh, lwl, lb,
        sc, nullptr, nullptr);

    // softmax stats, likelihood, boxes, reg
    softstats_k<<<dim3(Bb), blk, 0, stream>>>(sc, mx, sm);
    lik_k<<<dim3(Bb), blk, 0, stream>>>(sc, mx, sm, o_lik);
    box_k<<<dim3(Bb), blk, 0, stream>>>(sc, o_lik, mx, sm, gxy, imdp, o_box, o_nt, rp);
    reg_k<<<dim3(1), dim3(64), 0, stream>>>(rp, o_reg);
}

// Round 4
// 1604.566 us; speedup vs baseline: 2.5295x; 1.1451x over previous
//
#include <hip/hip_runtime.h>
#include <cmath>

#define TPB 256

// ---- problem constants (fixed by setup_inputs) ----
constexpr int Bb = 32, Cc = 256, Ff = 1024, Oo = 201;
constexpr int H0 = 10, S0 = 8,  N0 = Bb * S0 * S0;   // 2048
constexpr int H1 = 20, S1 = 18, N1 = Bb * S1 * S1;   // 10368
constexpr int NT_ALL = N0 + N1;                      // 12416
constexpr int KC = Cc * 9;                           // 2304 (natural K)
constexpr int KP = Cc * 16;                          // 4096 (tap-padded K: k' = c*16 + t, taps 9..15 zero)
constexpr int L5 = S0 * S0;                          // 64
constexpr int L4 = S1 * S1;                          // 324
constexpr int LT = L5 + L4;                          // 388

// ---- element counts ----
constexpr size_t SZ_CWP = (size_t)Ff * KP;      // 4,194,304 (padded)
constexpr size_t SZ_W0P = (size_t)Cc * KP;      // 1,048,576 (padded)
constexpr size_t SZ_LW  = (size_t)Oo * Ff;      // 205,824
constexpr size_t NFEAT  = (size_t)NT_ALL * Ff;  // 12,713,984

// ---- workspace byte offsets (time-disjoint aliasing) ----
constexpr size_t B_CWH   = 0;
constexpr size_t B_CWL   = B_CWH + SZ_CWP * 2;           //  8,388,608
constexpr size_t B_W0H   = B_CWL + SZ_CWP * 2;           // 16,777,216
constexpr size_t B_W0L   = B_W0H + SZ_W0P * 2;           // 18,874,368
constexpr size_t B_GXY   = B_W0L + SZ_W0P * 2;           // 20,971,520
constexpr size_t B_LWH   = B_GXY + (size_t)NT_ALL * 18 * 4; // 21,865,472
constexpr size_t B_LWL   = B_LWH + SZ_LW * 2;            // 22,277,120
constexpr size_t B_FEATH = B_LWL + SZ_LW * 2;            // 22,688,768
constexpr size_t B_FEATL = B_FEATH + NFEAT * 2;          // 48,116,736
constexpr size_t B_MX    = B_FEATL + NFEAT * 2;          // 73,544,704
constexpr size_t B_SM    = B_MX + 128;
constexpr size_t B_RP    = B_SM + 128;
constexpr size_t B_END   = B_RP + 128;                   // ~73.5 MB (known ws >= 78.4 MB)
// aliases (disjoint lifetimes):
constexpr size_t B_SC = B_CWH;    // sc (9.98 MB) over cw splits (dead when scores run)
constexpr size_t B_C2 = B_W0H;    // c2 (0.30 MB) over w0 splits (dead after conv1)
constexpr size_t B_H0 = B_FEATH;  // h (16.4 MB) over feat (written later)
constexpr size_t B_H1 = B_H0 + (size_t)Bb * Cc * H0 * H0 * 4;

// ---- output layout (floats) ----
constexpr size_t O_LIK = 0;
constexpr size_t O_BOX = O_LIK + Bb * Oo;
constexpr size_t O_NT  = O_BOX + Bb * 5;
constexpr size_t O_TD  = O_NT + Bb * 5;
constexpr size_t O_REG = O_TD + (size_t)NT_ALL * 6;

typedef __attribute__((ext_vector_type(8))) short bf16x8;
typedef __attribute__((ext_vector_type(4))) float f32x4;

__device__ __forceinline__ short f2bf(float f) {
    unsigned u = __builtin_bit_cast(unsigned, f);
    u += 0x7fffu + ((u >> 16) & 1u);
    return (short)(u >> 16);
}
__device__ __forceinline__ float bf2f(short s) {
    unsigned u = ((unsigned)(unsigned short)s) << 16;
    return __builtin_bit_cast(float, u);
}
__device__ __forceinline__ float clampf(float x, float lo, float hi) {
    return fminf(fmaxf(x, lo), hi);
}

// =====================================================================
// weight split kernels: fp32 -> (hi, lo) bf16.
// splitp16: src k = c*9 + t  ->  dst k' = c*16 + t,  taps 9..15 = 0
// =====================================================================
__global__ __launch_bounds__(TPB)
void splitp16_k(const float* __restrict__ src, short* __restrict__ hi,
                short* __restrict__ lo, int nrows)
{
    int idx = blockIdx.x * TPB + threadIdx.x;
    if (idx >= nrows * KP) return;
    int row = idx >> 12, kq = idx & (KP - 1);
    int c = kq >> 4, t = kq & 15;
    float v = (t < 9) ? src[(size_t)row * KC + c * 9 + t] : 0.f;
    short hs = f2bf(v);
    hi[idx] = hs;
    lo[idx] = f2bf(v - bf2f(hs));
}

__global__ __launch_bounds__(TPB)
void split_k(const float* __restrict__ src, short* __restrict__ hi,
             short* __restrict__ lo, int n)
{
    int idx = blockIdx.x * TPB + threadIdx.x;
    if (idx >= n) return;
    float v = src[idx];
    short hs = f2bf(v);
    hi[idx] = hs;
    lo[idx] = f2bf(v - bf2f(hs));
}

// =====================================================================
// Split-bf16 MFMA GEMM: out(MxN) = A(MxK) * Bw(NxK)^T (+bias, act)
// Block 128x128, BK=32, 4 waves, mfma_f32_16x16x32_bf16, 3 MFMAs/pair.
// MODE 0/2: K is tap-padded (KD=KP=4096, k=c*16+t). Per K-step only
//   channels {c0, c0+1} are needed; they are staged into an LDS slab
//   (coalesced float4) and A-elements are gathered FROM LDS with
//   per-row tap tables (compile-time tap indices -> registers).
// MODE 0: A = im2col pad=1 of Asrc (NCHW HxH); epilogue relu fp32 -> h
// MODE 2: A = bilinear sample of Asrc at gxy; epilogue feat hi/lo bf16
// MODE 3: A = pre-split rows (KD=1024, natural); epilogue score scatter
// GRID: dim3(nN, nM) -- n fastest; nN | 8 pins each XCD to one B-strip.
// =====================================================================
template<int MODE, int H, int S, int M, int N, int KD, int POS>
__global__ __launch_bounds__(TPB, 2)
void mgemm(const float* __restrict__ Asrc,
           const short* __restrict__ AsrcH, const short* __restrict__ AsrcL,
           const float* __restrict__ gxy,
           const short* __restrict__ Bh, const short* __restrict__ Bl,
           const float* __restrict__ bias,
           float* __restrict__ outF, short* __restrict__ outH, short* __restrict__ outL)
{
    constexpr int PLSZ = H * H;                       // image plane floats
    constexpr int RPI  = (MODE == 0) ? H * H : S * S; // rows per image
    constexpr int NBI  = (MODE == 3) ? 1 : (127 / RPI + 2); // max images/tile

    __shared__ short As[2][4][128][8];   // 16KB
    __shared__ short Bs[2][4][128][8];   // 16KB
    __shared__ float slab[(MODE == 3) ? 1 : NBI * 2 * PLSZ];

    const int tid = threadIdx.x;
    const int lane = tid & 63;
    const int wid = tid >> 6;
    const int wm = (wid >> 1) * 64, wn = (wid & 1) * 64;
    const int ml = tid & 127, kg0 = tid >> 7;
    const int bm = blockIdx.y * 128, bn = blockIdx.x * 128;   // n fastest

    f32x4 acc[4][4];
    #pragma unroll
    for (int i = 0; i < 4; i++)
        #pragma unroll
        for (int j = 0; j < 4; j++)
            acc[i][j] = (f32x4){0.f, 0.f, 0.f, 0.f};

    const int mG = bm + ml;
    const int nG = bn + ml;

    // ---- per-row tap tables (compile-time indexed => registers) ----
    int bat0 = 0, batidx = 0, nb = 1;
    float w00t[9], w01t[9], w10t[9], w11t[9];
    int o00t[9], o01t[9], o10t[9], o11t[9];
    float wvt[9];
    int offt[9];

    if constexpr (MODE == 0) {
        bat0 = bm / RPI;
        nb = (bm + 127) / RPI - bat0 + 1;
        int bA = mG / RPI; int rem = mG - bA * RPI;
        int yA = rem / H, xA = rem - (rem / H) * H;
        batidx = bA - bat0;
        #pragma unroll
        for (int t = 0; t < 9; t++) {
            int ky = t / 3 - 1, kx = t - (t / 3) * 3 - 1;
            int yy = yA + ky, xx = xA + kx;
            bool ok = (yy >= 0 && yy < H && xx >= 0 && xx < H);
            offt[t] = ok ? (yy * H + xx) : 0;
            wvt[t] = ok ? 1.f : 0.f;
        }
    } else if constexpr (MODE == 2) {
        bat0 = bm / RPI;
        nb = (bm + 127) / RPI - bat0 + 1;
        int bA = mG / RPI;
        batidx = bA - bat0;
        #pragma unroll
        for (int t = 0; t < 9; t++) {
            float gx = gxy[(size_t)mG * 18 + t];
            float gy = gxy[(size_t)mG * 18 + 9 + t];
            float xf = floorf(gx), yf = floorf(gy);
            float wx = gx - xf, wy = gy - yf;
            int ix = (int)xf, iy = (int)yf;
            int cx0 = min(max(ix, 0), H - 1), cx1 = min(max(ix + 1, 0), H - 1);
            int cy0 = min(max(iy, 0), H - 1), cy1 = min(max(iy + 1, 0), H - 1);
            float vx0 = (ix >= 0 && ix < H) ? 1.f : 0.f;
            float vx1 = (ix + 1 >= 0 && ix + 1 < H) ? 1.f : 0.f;
            float vy0 = (iy >= 0 && iy < H) ? 1.f : 0.f;
            float vy1 = (iy + 1 >= 0 && iy + 1 < H) ? 1.f : 0.f;
            w00t[t] = (1.f - wy) * (1.f - wx) * vy0 * vx0;
            w01t[t] = (1.f - wy) * wx * vy0 * vx1;
            w10t[t] = wy * (1.f - wx) * vy1 * vx0;
            w11t[t] = wy * wx * vy1 * vx1;
            o00t[t] = cy0 * H + cx0; o01t[t] = cy0 * H + cx1;
            o10t[t] = cy1 * H + cx0; o11t[t] = cy1 * H + cx1;
        }
    }

    for (int kb = 0; kb < KD; kb += 32) {
        // ---------- phase 0: slab stage (channels c0, c0+1) ----------
        if constexpr (MODE == 0 || MODE == 2) {
            const int c0 = kb >> 4;
            const int npl4 = nb * 2 * (PLSZ / 4);
            for (int i = tid; i < npl4; i += TPB) {
                int pl = i / (PLSZ / 4), p4 = i - pl * (PLSZ / 4);
                int bi = pl >> 1, cc = pl & 1;
                *(float4*)&slab[pl * PLSZ + p4 * 4] =
                    *(const float4*)(Asrc + ((size_t)(bat0 + bi) * Cc + c0 + cc) * PLSZ + p4 * 4);
            }
            __syncthreads();
        }
        // ---------- phase 1: A-stage from slab; B-stage ----------
        if constexpr (MODE == 0) {
            const float* sp = &slab[(batidx * 2 + kg0) * PLSZ];
            bf16x8 hv, lv;
            #pragma unroll
            for (int e = 0; e < 8; e++) {
                float v = sp[offt[e]] * wvt[e];
                short hs = f2bf(v); hv[e] = hs; lv[e] = f2bf(v - bf2f(hs));
            }
            *(bf16x8*)&As[0][kg0 * 2][ml][0] = hv;
            *(bf16x8*)&As[1][kg0 * 2][ml][0] = lv;
            bf16x8 hv2 = {}, lv2 = {};
            {
                float v = sp[offt[8]] * wvt[8];
                short hs = f2bf(v); hv2[0] = hs; lv2[0] = f2bf(v - bf2f(hs));
            }
            *(bf16x8*)&As[0][kg0 * 2 + 1][ml][0] = hv2;
            *(bf16x8*)&As[1][kg0 * 2 + 1][ml][0] = lv2;
        } else if constexpr (MODE == 2) {
            const float* sp = &slab[(batidx * 2 + kg0) * PLSZ];
            bf16x8 hv, lv;
            #pragma unroll
            for (int e = 0; e < 8; e++) {
                float v = sp[o00t[e]] * w00t[e] + sp[o01t[e]] * w01t[e]
                        + sp[o10t[e]] * w10t[e] + sp[o11t[e]] * w11t[e];
                short hs = f2bf(v); hv[e] = hs; lv[e] = f2bf(v - bf2f(hs));
            }
            *(bf16x8*)&As[0][kg0 * 2][ml][0] = hv;
            *(bf16x8*)&As[1][kg0 * 2][ml][0] = lv;
            bf16x8 hv2 = {}, lv2 = {};
            {
                float v = sp[o00t[8]] * w00t[8] + sp[o01t[8]] * w01t[8]
                        + sp[o10t[8]] * w10t[8] + sp[o11t[8]] * w11t[8];
                short hs = f2bf(v); hv2[0] = hs; lv2[0] = f2bf(v - bf2f(hs));
            }
            *(bf16x8*)&As[0][kg0 * 2 + 1][ml][0] = hv2;
            *(bf16x8*)&As[1][kg0 * 2 + 1][ml][0] = lv2;
        } else { // MODE 3
            #pragma unroll
            for (int hh = 0; hh < 2; hh++) {
                int kg = kg0 * 2 + hh;
                *(bf16x8*)&As[0][kg][ml][0] = *(const bf16x8*)(AsrcH + (size_t)mG * KD + kb + kg * 8);
                *(bf16x8*)&As[1][kg][ml][0] = *(const bf16x8*)(AsrcL + (size_t)mG * KD + kb + kg * 8);
            }
        }
        #pragma unroll
        for (int hh = 0; hh < 2; hh++) {
            int kg = kg0 * 2 + hh;
            bf16x8 hv = {}, lv = {};
            if (nG < N) {
                hv = *(const bf16x8*)(Bh + (size_t)nG * KD + kb + kg * 8);
                lv = *(const bf16x8*)(Bl + (size_t)nG * KD + kb + kg * 8);
            }
            *(bf16x8*)&Bs[0][kg][ml][0] = hv;
            *(bf16x8*)&Bs[1][kg][ml][0] = lv;
        }
        __syncthreads();
        // ---------- phase 2: MFMA ----------
        {
            const int kq = lane >> 4, r = lane & 15;
            bf16x8 ah[4], al[4], bhf[4], blf[4];
            #pragma unroll
            for (int i = 0; i < 4; i++) {
                ah[i]  = *(const bf16x8*)&As[0][kq][wm + i * 16 + r][0];
                al[i]  = *(const bf16x8*)&As[1][kq][wm + i * 16 + r][0];
                bhf[i] = *(const bf16x8*)&Bs[0][kq][wn + i * 16 + r][0];
                blf[i] = *(const bf16x8*)&Bs[1][kq][wn + i * 16 + r][0];
            }
            #pragma unroll
            for (int i = 0; i < 4; i++)
                #pragma unroll
                for (int j = 0; j < 4; j++) {
                    acc[i][j] = __builtin_amdgcn_mfma_f32_16x16x32_bf16(ah[i], bhf[j], acc[i][j], 0, 0, 0);
                    acc[i][j] = __builtin_amdgcn_mfma_f32_16x16x32_bf16(al[i], bhf[j], acc[i][j], 0, 0, 0);
                    acc[i][j] = __builtin_amdgcn_mfma_f32_16x16x32_bf16(ah[i], blf[j], acc[i][j], 0, 0, 0);
                }
        }
        __syncthreads();
    }

    // ---------- epilogue ----------
    const int kq = lane >> 4, rr = lane & 15;
    #pragma unroll
    for (int i = 0; i < 4; i++) {
        #pragma unroll
        for (int r = 0; r < 4; r++) {
            const int gm = bm + wm + i * 16 + kq * 4 + r;
            #pragma unroll
            for (int j = 0; j < 4; j++) {
                const int gn = bn + wn + j * 16 + rr;
                float v = acc[i][j][r];
                if constexpr (MODE == 0) {
                    int bq = gm / (H * H); int rem = gm - bq * (H * H);
                    int yq = rem / H; int xq = rem - yq * H;
                    outF[(((size_t)bq * Cc + gn) * H + yq) * H + xq] = fmaxf(v + bias[gn], 0.f);
                } else if constexpr (MODE == 2) {
                    float q = fmaxf(v + bias[gn], 0.f);
                    short hs = f2bf(q);
                    outH[(size_t)gm * Ff + gn] = hs;
                    outL[(size_t)gm * Ff + gn] = f2bf(q - bf2f(hs));
                } else {
                    if (gn < N) {
                        int bq = gm / (S * S); int rem = gm - bq * (S * S);
                        int xq = rem / S; int yq = rem - xq * S;
                        outF[((size_t)bq * Oo + gn) * LT + (yq * S + xq + POS)] = v + bias[gn];
                    }
                }
            }
        }
    }
}

// =====================================================================
// conv2: N=6 tiny conv. 32 rows/block, 8 ci-groups, w1 in LDS.
// =====================================================================
__global__ __launch_bounds__(TPB)
void conv2_k(const float* __restrict__ h0, const float* __restrict__ h1,
             const float* __restrict__ w1, float* __restrict__ c2)
{
    __shared__ float wl[6][KC];
    __shared__ float part[8][32][6];
    const int tid = threadIdx.x;
    for (int i = tid; i < 6 * KC; i += TPB) wl[i / KC][i - (i / KC) * KC] = w1[i];
    __syncthreads();
    const int row = blockIdx.x * 32 + (tid & 31);
    const int cig = tid >> 5;
    const float* hsrc; int H, S, loc;
    if (row < N0) { hsrc = h0; H = H0; S = S0; loc = row; }
    else          { hsrc = h1; H = H1; S = S1; loc = row - N0; }
    int SS = S * S;
    int b = loc / SS; int rem = loc - b * SS;
    int xq = rem / S; int yq = rem - xq * S;
    float acc[6] = {};
    for (int ci = cig * 32; ci < cig * 32 + 32; ci++) {
        const float* hp = hsrc + ((size_t)(b * Cc + ci) * H + yq) * H + xq;
        #pragma unroll
        for (int ky = 0; ky < 3; ky++)
            #pragma unroll
            for (int kx = 0; kx < 3; kx++) {
                float a = hp[ky * H + kx];
                int kk = ci * 9 + ky * 3 + kx;
                #pragma unroll
                for (int n = 0; n < 6; n++) acc[n] = fmaf(a, wl[n][kk], acc[n]);
            }
    }
    #pragma unroll
    for (int n = 0; n < 6; n++) part[cig][tid & 31][n] = acc[n];
    __syncthreads();
    if (cig == 0) {
        #pragma unroll
        for (int n = 0; n < 6; n++) {
            float s = 0.f;
            for (int g = 0; g < 8; g++) s += part[g][tid & 31][n];
            c2[(size_t)row * 6 + n] = s;
        }
    }
}

// ====================================================================
// theta / theta_diff / sampling coords (verified rounds 1-3)
// ====================================================================
__global__ __launch_bounds__(TPB)
void theta_aux_k(const float* __restrict__ c2, const int* __restrict__ checkp,
                 float* __restrict__ td, float* __restrict__ gxy)
{
    int n = blockIdx.x * TPB + threadIdx.x;
    if (n >= NT_ALL) return;
    float omc = 1.0f - (float)checkp[0];
    const float I[6] = {1.f, 0.f, 0.f, 0.f, 1.f, 0.f};
    float th[6];
    #pragma unroll
    for (int i = 0; i < 6; i++) {
        float v = c2[(size_t)n * 6 + i] * omc + I[i];
        th[i] = v;
        td[(size_t)n * 6 + i] = I[i] - v;
    }
    int S, loc;
    if (n < N0) { S = S0; loc = n; } else { S = S1; loc = n - N0; }
    int SS = S * S;
    int rem = loc % SS;
    int xx = rem / S, yy = rem % S;
    #pragma unroll
    for (int ky = 0; ky < 3; ky++)
        #pragma unroll
        for (int kx = 0; kx < 3; kx++) {
            float bx = (float)(kx - 1), by = (float)(ky - 1);
            gxy[(size_t)n * 18 + ky * 3 + kx]     = th[0] * bx + th[1] * by + th[2] + 1.0f + (float)xx;
            gxy[(size_t)n * 18 + 9 + ky * 3 + kx] = th[3] * bx + th[4] * by + th[5] + 1.0f + (float)yy;
        }
}

__global__ __launch_bounds__(TPB)
void softstats_k(const float* __restrict__ sc, float* __restrict__ mx, float* __restrict__ sm)
{
    int b = blockIdx.x, tid = threadIdx.x;
    const float* p = sc + (size_t)b * Oo * LT;
    constexpr int PER = Oo * LT;
    __shared__ float red[TPB];
    float m = -3.4e38f;
    for (int i = tid; i < PER; i += TPB) m = fmaxf(m, p[i]);
    red[tid] = m;
    for (int off = 128; off; off >>= 1) { __syncthreads(); if (tid < off) red[tid] = fmaxf(red[tid], red[tid + off]); }
    __syncthreads();
    m = red[0];
    __syncthreads();
    float s = 0.f;
    for (int i = tid; i < PER; i += TPB) s += expf(p[i] - m);
    red[tid] = s;
    for (int off = 128; off; off >>= 1) { __syncthreads(); if (tid < off) red[tid] += red[tid + off]; }
    __syncthreads();
    if (tid == 0) { mx[b] = m; sm[b] = red[0]; }
}

__global__ __launch_bounds__(TPB)
void lik_k(const float* __restrict__ sc, const float* __restrict__ mx,
           const float* __restrict__ sm, float* __restrict__ lik)
{
    int b = blockIdx.x, o = threadIdx.x;
    if (o >= Oo) return;
    const float* p = sc + ((size_t)b * Oo + o) * LT;
    float m = mx[b];
    float s = 0.f;
    for (int i = 0; i < LT; i++) s += expf(p[i] - m);
    lik[b * Oo + o] = s / sm[b];
}

__global__ __launch_bounds__(TPB)
void box_k(const float* __restrict__ sc, const float* __restrict__ lik,
           const float* __restrict__ mx, const float* __restrict__ sm,
           const float* __restrict__ gxy, const int* __restrict__ imdp,
           float* __restrict__ boxes, float* __restrict__ boxesNT,
           float* __restrict__ regpart)
{
    int b = blockIdx.x, tid = threadIdx.x;
    __shared__ float sv[TPB];
    __shared__ int si[TPB];

    float v = (tid < Oo) ? lik[b * Oo + tid] : -3.4e38f;
    sv[tid] = v; si[tid] = tid;
    for (int off = 128; off; off >>= 1) {
        __syncthreads();
        if (tid < off) {
            float v2 = sv[tid + off]; int i2 = si[tid + off];
            if (v2 > sv[tid] || (v2 == sv[tid] && i2 < si[tid])) { sv[tid] = v2; si[tid] = i2; }
        }
    }
    __syncthreads();
    int pred = si[0];
    __syncthreads();

    const float* p = sc + ((size_t)b * Oo + pred) * LT;
    float b5 = -3.4e38f; int i5 = 1 << 30;
    float b4 = -3.4e38f; int i4 = 1 << 30;
    for (int pos = tid; pos < LT; pos += TPB) {
        float s = p[pos];
        if (pos < L5) { if (s > b5) { b5 = s; i5 = pos; } }
        else { int q = pos - L5; if (s > b4) { b4 = s; i4 = q; } }
    }
    sv[tid] = b5; si[tid] = i5;
    for (int off = 128; off; off >>= 1) {
        __syncthreads();
        if (tid < off) {
            float v2 = sv[tid + off]; int i2 = si[tid + off];
            if (v2 > sv[tid] || (v2 == sv[tid] && i2 < si[tid])) { sv[tid] = v2; si[tid] = i2; }
        }
    }
    __syncthreads();
    float m5 = sv[0]; int d5 = si[0];
    __syncthreads();
    sv[tid] = b4; si[tid] = i4;
    for (int off = 128; off; off >>= 1) {
        __syncthreads();
        if (tid < off) {
            float v2 = sv[tid + off]; int i2 = si[tid + off];
            if (v2 > sv[tid] || (v2 == sv[tid] && i2 < si[tid])) { sv[tid] = v2; si[tid] = i2; }
        }
    }
    __syncthreads();
    float m4 = sv[0]; int d4 = si[0];

    if (tid == 0) {
        float m = mx[b], s = sm[b];
        float conf5 = expf(m5 - m) / s;
        float conf4 = expf(m4 - m) / s;
        float imd = (float)imdp[0];
        float lo = 0.f, hi = imd - 1.f;

        int xx5 = d5 % S0, yy5 = d5 / S0;
        int n5 = b * (S0 * S0) + xx5 * S0 + yy5;
        const float* g = gxy + (size_t)n5 * 18;
        float txm = 1e30f, txM = -1e30f, tym = 1e30f, tyM = -1e30f;
        for (int j = 0; j < 9; j++) {
            float tx = g[j] / 9.f, ty = g[9 + j] / 9.f;
            txm = fminf(txm, tx); txM = fmaxf(txM, tx);
            tym = fminf(tym, ty); tyM = fmaxf(tyM, ty);
        }
        float box5[5] = { clampf(txm * imd, lo, hi), clampf(tym * imd, lo, hi),
                          clampf(txM * imd, lo, hi), clampf(tyM * imd, lo, hi), conf5 };
        float nt5[5]  = { clampf((float)xx5 / 9.f * imd, lo, hi), clampf((float)yy5 / 9.f * imd, lo, hi),
                          clampf((float)(xx5 + 2) / 9.f * imd, lo, hi), clampf((float)(yy5 + 2) / 9.f * imd, lo, hi), conf5 };

        int xx4 = d4 % S1, yy4 = d4 / S1;
        int n4 = N0 + b * (S1 * S1) + xx4 * S1 + yy4;
        const float* g4 = gxy + (size_t)n4 * 18;
        float txm4 = 1e30f, txM4 = -1e30f, tym4 = 1e30f, tyM4 = -1e30f;
        for (int j = 0; j < 9; j++) {
            float tx = g4[j] / 19.f, ty = g4[9 + j] / 19.f;
            txm4 = fminf(txm4, tx); txM4 = fmaxf(txM4, tx);
            tym4 = fminf(tym4, ty); tyM4 = fmaxf(tyM4, ty);
        }
        float box4[5] = { clampf(txm4 * imd, lo, hi), clampf(tym4 * imd, lo, hi),
                          clampf(txM4 * imd, lo, hi), clampf(tyM4 * imd, lo, hi), conf4 };
        float nt4[5]  = { clampf((float)xx4 / 19.f * imd, lo, hi), clampf((float)yy4 / 19.f * imd, lo, hi),
                          clampf((float)(xx4 + 2) / 19.f * imd, lo, hi), clampf((float)(yy4 + 2) / 19.f * imd, lo, hi), conf4 };

        int mi = (conf4 > conf5) ? 1 : 0;
        for (int i = 0; i < 5; i++) {
            boxes[b * 5 + i]   = mi ? box4[i] : box5[i];
            boxesNT[b * 5 + i] = mi ? nt4[i] : nt5[i];
        }
        regpart[b] = fmaxf(conf4 - conf5, 0.f);
    }
}

__global__ void reg_k(const float* __restrict__ regpart, float* __restrict__ outreg)
{
    if (threadIdx.x == 0) {
        float s = 0.f;
        for (int b = 0; b < Bb; b++) s += regpart[b];
        outreg[0] = s;
    }
}

__global__ void sentinel_k(float* out, int n)
{
    int i = blockIdx.x * 256 + threadIdx.x;
    if (i < n) out[i] = 12345.0f;
}

extern "C" void kernel_launch(void* const* d_in, const int* in_sizes, int n_in,
                              void* d_out, int out_size, void* d_ws, size_t ws_size,
                              hipStream_t stream)
{
    const float* x0 = (const float*)d_in[0];
    const float* x1 = (const float*)d_in[1];
    const float* w0 = (const float*)d_in[2];
    const float* b0 = (const float*)d_in[3];
    const float* w1 = (const float*)d_in[4];
    const float* cw = (const float*)d_in[5];
    const float* cb = (const float*)d_in[6];
    const float* lw = (const float*)d_in[7];
    const float* lb = (const float*)d_in[8];
    const int* checkp = (const int*)d_in[9];
    const int* imdp   = (const int*)d_in[10];

    if (ws_size < B_END) {
        sentinel_k<<<dim3((out_size + 255) / 256), dim3(256), 0, stream>>>((float*)d_out, out_size);
        return;
    }

    char* wsb = (char*)d_ws;
    short* cwh = (short*)(wsb + B_CWH);
    short* cwl = (short*)(wsb + B_CWL);
    short* w0h = (short*)(wsb + B_W0H);
    short* w0l = (short*)(wsb + B_W0L);
    float* gxy = (float*)(wsb + B_GXY);
    short* lwh = (short*)(wsb + B_LWH);
    short* lwl = (short*)(wsb + B_LWL);
    short* fH  = (short*)(wsb + B_FEATH);
    short* fL  = (short*)(wsb + B_FEATL);
    float* mx  = (float*)(wsb + B_MX);
    float* sm  = (float*)(wsb + B_SM);
    float* rp  = (float*)(wsb + B_RP);
    float* sc  = (float*)(wsb + B_SC);
    float* c2  = (float*)(wsb + B_C2);
    float* h0  = (float*)(wsb + B_H0);
    float* h1  = (float*)(wsb + B_H1);

    float* out   = (float*)d_out;
    float* o_lik = out + O_LIK;
    float* o_box = out + O_BOX;
    float* o_nt  = out + O_NT;
    float* o_td  = out + O_TD;
    float* o_reg = out + O_REG;

    dim3 blk(TPB);

    // weight splits (w0/cw: tap-padded 16, k'=c*16+t; lw natural)
    splitp16_k<<<dim3((int)(SZ_W0P + TPB - 1) / TPB), blk, 0, stream>>>(w0, w0h, w0l, Cc);
    splitp16_k<<<dim3((int)(SZ_CWP + TPB - 1) / TPB), blk, 0, stream>>>(cw, cwh, cwl, Ff);
    split_k   <<<dim3((int)(SZ_LW + TPB - 1) / TPB), blk, 0, stream>>>(lw, lwh, lwl, (int)SZ_LW);

    // conv1 (+bias, relu) -> h fp32, both scales   [grid = (nN, nM)]
    mgemm<0, H0, 1, Bb * H0 * H0, Cc, KP, 0><<<dim3(2, 25), blk, 0, stream>>>(
        x0, nullptr, nullptr, nullptr, w0h, w0l, b0, h0, nullptr, nullptr);
    mgemm<0, H1, 1, Bb * H1 * H1, Cc, KP, 0><<<dim3(2, 100), blk, 0, stream>>>(
        x1, nullptr, nullptr, nullptr, w0h, w0l, b0, h1, nullptr, nullptr);

    // conv2 (6 ch) -> c2
    conv2_k<<<dim3(NT_ALL / 32), blk, 0, stream>>>(h0, h1, w1, c2);

    // theta, theta_diff, sampling coords
    theta_aux_k<<<dim3((NT_ALL + TPB - 1) / TPB), blk, 0, stream>>>(c2, checkp, o_td, gxy);

    // fused bilinear-sample GEMM -> feat hi/lo (clobbers h: dead)
    mgemm<2, H0, S0, N0, Ff, KP, 0><<<dim3(8, 16), blk, 0, stream>>>(
        x0, nullptr, nullptr, gxy, cwh, cwl, cb, nullptr, fH, fL);
    mgemm<2, H1, S1, N1, Ff, KP, 0><<<dim3(8, 81), blk, 0, stream>>>(
        x1, nullptr, nullptr, gxy + (size_t)N0 * 18, cwh, cwl, cb,
        nullptr, fH + (size_t)N0 * Ff, fL + (size_t)N0 * Ff);

    // feat -> scores scatter (sc clobbers cw splits: dead)
    mgemm<3, 1, S0, N0, Oo, Ff, 0><<<dim3(2, 16), blk, 0, stream>>>(
        nullptr, fH, fL, nullptr, lwh, lwl, lb, sc, nullptr, nullptr);
    mgemm<3, 1, S1, N1, Oo, Ff, L5><<<dim3(2, 81), blk, 0, stream>>>(
        nullptr, fH + (size_t)N0 * Ff, fL + (size_t)N0 * Ff, nullptr, lwh, lwl, lb,
        sc, nullptr, nullptr);

    // softmax stats, likelihood, boxes, reg
    softstats_k<<<dim3(Bb), blk, 0, stream>>>(sc, mx, sm);
    lik_k<<<dim3(Bb), blk, 0, stream>>>(sc, mx, sm, o_lik);
    box_k<<<dim3(Bb), blk, 0, stream>>>(sc, o_lik, mx, sm, gxy, imdp, o_box, o_nt, rp);
    reg_k<<<dim3(1), dim3(64), 0, stream>>>(rp, o_reg);
}